// Round 2
// baseline (176775.195 us; speedup 1.0000x reference)
//
#include <hip/hip_runtime.h>

typedef short bf16x8 __attribute__((ext_vector_type(8)));
typedef float f32x4 __attribute__((ext_vector_type(4)));

#define DEV static __device__ __forceinline__
#define SCOPE_AGENT __HIP_MEMORY_SCOPE_AGENT

// ---------------- numeric helpers ----------------
DEV unsigned short f2bf(float f) {
  unsigned u = __float_as_uint(f);
  unsigned r = u + 0x7fffu + ((u >> 16) & 1u);
  return (unsigned short)(r >> 16);
}
DEV float bf2f(unsigned short h) { return __uint_as_float(((unsigned)h) << 16); }
DEV void f2hilo(float f, unsigned short& hi, unsigned short& lo) {
  hi = f2bf(f);
  lo = f2bf(f - bf2f(hi));
}
DEV float sigm(float x) { return 1.f / (1.f + __expf(-x)); }
DEV float tanh_(float x) {
  x = fminf(15.f, fmaxf(-15.f, x));
  float e = __expf(2.f * x);
  return (e - 1.f) / (e + 1.f);
}

// ---------------- coherent (sc1 / LLC) access helpers ----------------
// All cross-wave dynamic state goes through agent-scope relaxed atomics:
// they compile to global_load/store with sc1 (bypass non-coherent per-XCD L2,
// coherent at LLC). Weights/x use plain loads -> stay L2-resident, never flushed.
DEV void st_sc_u16(unsigned short* p, unsigned short v) {
  __hip_atomic_store(p, v, __ATOMIC_RELAXED, SCOPE_AGENT);
}
DEV void st_sc_f32(float* p, float v) {
  __hip_atomic_store(p, v, __ATOMIC_RELAXED, SCOPE_AGENT);
}
DEV float ld_sc_f32(const float* p) {
  return __hip_atomic_load((float*)p, __ATOMIC_RELAXED, SCOPE_AGENT);
}
DEV unsigned short ld_sc_u16(const unsigned short* p) {
  return __hip_atomic_load((unsigned short*)p, __ATOMIC_RELAXED, SCOPE_AGENT);
}
DEV bf16x8 ldb8(const unsigned short* p, int coh) {
  if (coh) {
    union { bf16x8 v; unsigned long long q[2]; } u;
    unsigned long long* pp = (unsigned long long*)p;
    u.q[0] = __hip_atomic_load(pp, __ATOMIC_RELAXED, SCOPE_AGENT);
    u.q[1] = __hip_atomic_load(pp + 1, __ATOMIC_RELAXED, SCOPE_AGENT);
    return u.v;
  }
  return *(const bf16x8*)p;
}

// ---------------- workspace layout ----------------
constexpr size_t WE1 = 1024 * 352, WE2 = 1024 * 512, WE3 = 1024 * 512,
                 WD1 = 1024 * 768, WD2 = 1024 * 512, WD3 = 320 * 352,
                 WKEY = 256 * 256, WVAL = 256 * 256, WEMB = 256 * 96;
constexpr size_t E1HI = 0, E1LO = E1HI + WE1, E2HI = E1LO + WE1, E2LO = E2HI + WE2,
                 E3HI = E2LO + WE2, E3LO = E3HI + WE3, D1HI = E3LO + WE3, D1LO = D1HI + WD1,
                 D2HI = D1LO + WD1, D2LO = D2HI + WD2, D3HI = D2LO + WD2, D3LO = D3HI + WD3,
                 KHI = D3LO + WD3, KLO = KHI + WKEY, VHI = KLO + WKEY, VLO = VHI + WVAL,
                 EMHI = VLO + WVAL, EMLO = EMHI + WEMB, WTOT = EMLO + WEMB;

constexpr size_t XPAD_ELEMS = (size_t)400 * 64 * 96;
constexpr size_t XPAD_HI_B = WTOT * 2;
constexpr size_t XPAD_LO_B = XPAD_HI_B + XPAD_ELEMS * 2;
constexpr size_t STATE_B = XPAD_LO_B + XPAD_ELEMS * 2;

// state sub-offsets (bytes relative to st = ws + STATE_B); zeroed by memset
constexpr size_t H256_SZB = (size_t)2 * 2 * 64 * 256 * 2;  // [parity][hi/lo][64][256] ushort
constexpr size_t HE1 = 0, HE2 = H256_SZB, HE3 = 2 * H256_SZB, HD1 = 3 * H256_SZB,
                 HD2 = 4 * H256_SZB;
constexpr size_t HLAST = 5 * H256_SZB;                       // [2][2][64][96] ushort
constexpr size_t HLAST_SZB = (size_t)2 * 2 * 64 * 96 * 2;
constexpr size_t CBASE = HLAST + HLAST_SZB;
constexpr size_t C256 = (size_t)64 * 256 * 4;
constexpr size_t CE1 = CBASE, CE2 = CBASE + C256, CE3 = CBASE + 2 * C256,
                 CD1 = CBASE + 3 * C256, CD2 = CBASE + 4 * C256, CD3 = CBASE + 5 * C256;
constexpr size_t CD3_SZ = (size_t)64 * 80 * 4;
constexpr size_t BARO = CD3 + CD3_SZ;       // barrier counter (zeroed each launch)
constexpr size_t STATE_BYTES = BARO + 256;

// non-zeroed extras
constexpr size_t RINGK_B = STATE_B + STATE_BYTES;
constexpr size_t RING_SZ = (size_t)20 * 64 * 256 * 4;
constexpr size_t RINGV_B = RINGK_B + RING_SZ;
constexpr size_t EMBH_B = RINGV_B + RING_SZ;
constexpr size_t EMBL_B = EMBH_B + (size_t)64 * 256 * 2;
constexpr size_t CTXH_B = EMBL_B + (size_t)64 * 256 * 2;
constexpr size_t CTXL_B = CTXH_B + (size_t)64 * 256 * 2;
constexpr size_t WS_NEED = CTXL_B + (size_t)64 * 256 * 2;

// ---------------- prep kernels ----------------
__global__ void prep_w(const float* __restrict__ wih, int din, const float* __restrict__ whh,
                       int dh, int rows, int dinp, int kp, unsigned short* __restrict__ whi,
                       unsigned short* __restrict__ wlo) {
  size_t idx = (size_t)blockIdx.x * 256 + threadIdx.x;
  size_t tot = (size_t)rows * kp;
  if (idx >= tot) return;
  int j = (int)(idx / kp), k = (int)(idx % kp);
  float v = 0.f;
  if (k < dinp) {
    if (k < din) v = wih[(size_t)j * din + k];
  } else {
    int k2 = k - dinp;
    if (k2 < dh) v = whh[(size_t)j * dh + k2];
  }
  unsigned short hi, lo;
  f2hilo(v, hi, lo);
  whi[idx] = hi;
  wlo[idx] = lo;
}

__global__ void prep_x(const float* __restrict__ x, unsigned short* __restrict__ xh,
                       unsigned short* __restrict__ xl) {
  size_t idx = (size_t)blockIdx.x * 256 + threadIdx.x;
  if (idx >= XPAD_ELEMS) return;
  int t = (int)(idx / 6144), rbf = (int)(idx % 6144), b = rbf / 96, f = rbf % 96;
  float v = (f < 80) ? x[(size_t)b * 32000 + (size_t)t * 80 + f] : 0.f;
  unsigned short hi, lo;
  f2hilo(v, hi, lo);
  xh[idx] = hi;
  xl[idx] = lo;
}

// ---------------- main kernel ----------------
struct Src {
  const unsigned short* hi;
  const unsigned short* lo;
  int kp;
  int coh;  // 1 = cross-wave data, load via sc1; 0 = static (x), plain cached loads
};

DEV unsigned short* hbuf(unsigned char* st, size_t cellOff, int par, int hl, int Hpad) {
  return (unsigned short*)(st + cellOff) + (size_t)(par * 2 + hl) * 64 * Hpad;
}

DEV void mfma3(f32x4& acc, bf16x8 ah, bf16x8 al, bf16x8 bh, bf16x8 bl) {
  acc = __builtin_amdgcn_mfma_f32_16x16x32_bf16(ah, bh, acc, 0, 0, 0);
  acc = __builtin_amdgcn_mfma_f32_16x16x32_bf16(al, bh, acc, 0, 0, 0);
  acc = __builtin_amdgcn_mfma_f32_16x16x32_bf16(ah, bl, acc, 0, 0, 0);
}

#define NWG 12
#define WGS 512

// grid barrier: monotonic LLC atomic counter; no L2 flush anywhere.
DEV void gridbar(unsigned* cnt, unsigned target) {
  asm volatile("" ::: "memory");
  __syncthreads();  // per-wave s_waitcnt vmcnt(0) -> all sc1 stores LLC-visible
  if (threadIdx.x == 0) {
    __hip_atomic_fetch_add(cnt, 1u, __ATOMIC_RELAXED, SCOPE_AGENT);
    while (__hip_atomic_load(cnt, __ATOMIC_RELAXED, SCOPE_AGENT) < target)
      __builtin_amdgcn_s_sleep(1);
  }
  __syncthreads();
  asm volatile("" ::: "memory");
}

// LSTM tile: one 16-unit column tile (ut), all 64 batches, all 4 gates.
template <int NSRC>
DEV void lstm_tile(int lane, int ut, int H, int Hpad, const Src (&srcs)[NSRC],
                   const unsigned short* __restrict__ Whi, const unsigned short* __restrict__ Wlo,
                   int Kp, const float* __restrict__ bias, float* __restrict__ c,
                   unsigned short* hwhi, unsigned short* hwlo, float* outp) {
  f32x4 acc[4][4];
#pragma unroll
  for (int g = 0; g < 4; g++)
#pragma unroll
    for (int m = 0; m < 4; m++) acc[g][m] = f32x4{0.f, 0.f, 0.f, 0.f};

  const int col = lane & 15, kg = lane >> 4;
  int kw = kg * 8;  // running k into W rows
#pragma unroll
  for (int s = 0; s < NSRC; s++) {
    const int kp = srcs[s].kp;
    const int coh = srcs[s].coh;
    const unsigned short* shi = srcs[s].hi;
    const unsigned short* slo = srcs[s].lo;
#pragma unroll 2
    for (int kb = 0; kb < kp; kb += 32) {
      const int ka = kb + kg * 8;
      bf16x8 ah[4], al[4];
#pragma unroll
      for (int m = 0; m < 4; m++) {
        int row = m * 16 + col;
        ah[m] = ldb8(shi + (size_t)row * kp + ka, coh);
        al[m] = ldb8(slo + (size_t)row * kp + ka, coh);
      }
#pragma unroll
      for (int g = 0; g < 4; g++) {
        int brow = g * H + ut * 16 + col;
        bf16x8 bh = *(const bf16x8*)(Whi + (size_t)brow * Kp + kw);
        bf16x8 bl = *(const bf16x8*)(Wlo + (size_t)brow * Kp + kw);
#pragma unroll
        for (int m = 0; m < 4; m++) mfma3(acc[g][m], ah[m], al[m], bh, bl);
      }
      kw += 32;
    }
  }
  // elementwise cell update (lane-local: all 4 gates of (b,u) share lane/reg)
  const int u = ut * 16 + col;
  const float bi = bias[u], bff = bias[H + u], bg = bias[2 * H + u], bo = bias[3 * H + u];
#pragma unroll
  for (int m = 0; m < 4; m++) {
#pragma unroll
    for (int r = 0; r < 4; r++) {
      int b = m * 16 + kg * 4 + r;
      float gi = acc[0][m][r] + bi;
      float gf = acc[1][m][r] + bff;
      float gg = acc[2][m][r] + bg;
      float go = acc[3][m][r] + bo;
      float cold = c[b * H + u];  // c is same-wave private: plain cached access
      float cn = sigm(gf) * cold + sigm(gi) * tanh_(gg);
      float hh = sigm(go) * tanh_(cn);
      c[b * H + u] = cn;
      unsigned short hi, lo;
      f2hilo(hh, hi, lo);
      st_sc_u16(hwhi + b * Hpad + u, hi);
      st_sc_u16(hwlo + b * Hpad + u, lo);
      if (outp) outp[(size_t)b * 30400 + u] = hh;  // plain: host reads after kernel end
    }
  }
}

// Linear tile: one 16-col tile (jt), all 64 batches, + bias.
DEV void linear_tile(int lane, int jt, const Src& src, const unsigned short* __restrict__ Whi,
                     const unsigned short* __restrict__ Wlo, int Kp, const float* __restrict__ bias,
                     float* out_f32, unsigned short* ohi, unsigned short* olo) {
  f32x4 acc[4];
#pragma unroll
  for (int m = 0; m < 4; m++) acc[m] = f32x4{0.f, 0.f, 0.f, 0.f};
  const int col = lane & 15, kg = lane >> 4;
#pragma unroll 2
  for (int kb = 0; kb < Kp; kb += 32) {
    int ka = kb + kg * 8;
    bf16x8 bh = *(const bf16x8*)(Whi + (size_t)(jt * 16 + col) * Kp + ka);
    bf16x8 bl = *(const bf16x8*)(Wlo + (size_t)(jt * 16 + col) * Kp + ka);
#pragma unroll
    for (int m = 0; m < 4; m++) {
      int row = m * 16 + col;
      bf16x8 ah = ldb8(src.hi + (size_t)row * src.kp + ka, src.coh);
      bf16x8 al = ldb8(src.lo + (size_t)row * src.kp + ka, src.coh);
      mfma3(acc[m], ah, al, bh, bl);
    }
  }
  int j = jt * 16 + col;
  float bj = bias[j];
#pragma unroll
  for (int m = 0; m < 4; m++)
#pragma unroll
    for (int r = 0; r < 4; r++) {
      int b = m * 16 + kg * 4 + r;
      float v = acc[m][r] + bj;
      if (out_f32) st_sc_f32(out_f32 + (size_t)b * 256 + j, v);
      if (ohi) {
        unsigned short hi, lo;
        f2hilo(v, hi, lo);
        st_sc_u16(ohi + b * 256 + j, hi);
        st_sc_u16(olo + b * 256 + j, lo);
      }
    }
}

// attention for one batch row b (whole wave)
DEV void attn_wave(int lane, int b, const unsigned short* qh, const unsigned short* ql,
                   const float* ringk, const float* ringv, unsigned short* ctxh,
                   unsigned short* ctxl) {
  float qv[4];
#pragma unroll
  for (int j = 0; j < 4; j++) {
    int e = lane + 64 * j;
    qv[j] = bf2f(ld_sc_u16(qh + b * 256 + e)) + bf2f(ld_sc_u16(ql + b * 256 + e));
  }
  float s[20];
#pragma unroll
  for (int kk = 0; kk < 20; kk++) {
    const float* kr = ringk + ((size_t)kk * 64 + b) * 256;
    float part = 0.f;
#pragma unroll
    for (int j = 0; j < 4; j++) part += ld_sc_f32(kr + lane + 64 * j) * qv[j];
#pragma unroll
    for (int off = 32; off; off >>= 1) part += __shfl_xor(part, off, 64);
    s[kk] = part;
  }
  float mx = s[0];
#pragma unroll
  for (int kk = 1; kk < 20; kk++) mx = fmaxf(mx, s[kk]);
  float den = 0.f;
#pragma unroll
  for (int kk = 0; kk < 20; kk++) {
    s[kk] = __expf(s[kk] - mx);
    den += s[kk];
  }
  float inv = 1.f / den;
#pragma unroll
  for (int j = 0; j < 4; j++) {
    int e = lane + 64 * j;
    float a = 0.f;
#pragma unroll
    for (int kk = 0; kk < 20; kk++) a += s[kk] * ld_sc_f32(ringv + ((size_t)kk * 64 + b) * 256 + e);
    a *= inv;
    unsigned short hi, lo;
    f2hilo(a, hi, lo);
    st_sc_u16(ctxh + b * 256 + e, hi);
    st_sc_u16(ctxl + b * 256 + e, lo);
  }
}

__global__ void __launch_bounds__(WGS, 1)
seq_main(const float* e1b, const float* e2b, const float* e3b, const float* d1b,
         const float* d2b, const float* d3b, const float* embb, const float* keyb,
         const float* valb, float* dout, unsigned char* ws) {
  const int wid = blockIdx.x * (WGS / 64) + (threadIdx.x >> 6);
  const int lane = threadIdx.x & 63;

  unsigned short* W = (unsigned short*)ws;
  const unsigned short* xh = (const unsigned short*)(ws + XPAD_HI_B);
  const unsigned short* xl = (const unsigned short*)(ws + XPAD_LO_B);
  unsigned char* st = ws + STATE_B;
  float* ringk = (float*)(ws + RINGK_B);
  float* ringv = (float*)(ws + RINGV_B);
  unsigned short* embh = (unsigned short*)(ws + EMBH_B);
  unsigned short* embl = (unsigned short*)(ws + EMBL_B);
  unsigned short* ctxh = (unsigned short*)(ws + CTXH_B);
  unsigned short* ctxl = (unsigned short*)(ws + CTXL_B);
  unsigned* cnt = (unsigned*)(st + BARO);

  unsigned bt = 0;
  auto BAR = [&]() {
    bt += NWG;
    gridbar(cnt, bt);
  };

  for (int t = 0; t < 400; ++t) {
    const int p = t & 1, q = p ^ 1;
    const int slot = t % 20;
    if (t < 21) {
      // ---------- encoder rhythm (phase 1 + t==20 encoder part) ----------
      if (wid < 16) {
        Src ss[2] = {{xh + (size_t)t * 6144, xl + (size_t)t * 6144, 96, 0},
                     {hbuf(st, HE1, q, 0, 256), hbuf(st, HE1, q, 1, 256), 256, 1}};
        lstm_tile(lane, wid, 256, 256, ss, W + E1HI, W + E1LO, 352, e1b, (float*)(st + CE1),
                  hbuf(st, HE1, p, 0, 256), hbuf(st, HE1, p, 1, 256), nullptr);
      }
      BAR();
      if (wid < 16) {
        Src ss[2] = {{hbuf(st, HE1, p, 0, 256), hbuf(st, HE1, p, 1, 256), 256, 1},
                     {hbuf(st, HE2, q, 0, 256), hbuf(st, HE2, q, 1, 256), 256, 1}};
        lstm_tile(lane, wid, 256, 256, ss, W + E2HI, W + E2LO, 512, e2b, (float*)(st + CE2),
                  hbuf(st, HE2, p, 0, 256), hbuf(st, HE2, p, 1, 256), nullptr);
      }
      BAR();
      if (wid < 16) {
        Src ss[2] = {{hbuf(st, HE2, p, 0, 256), hbuf(st, HE2, p, 1, 256), 256, 1},
                     {hbuf(st, HE3, q, 0, 256), hbuf(st, HE3, q, 1, 256), 256, 1}};
        lstm_tile(lane, wid, 256, 256, ss, W + E3HI, W + E3LO, 512, e3b, (float*)(st + CE3),
                  hbuf(st, HE3, p, 0, 256), hbuf(st, HE3, p, 1, 256), nullptr);
      }
      BAR();
      if (wid < 16) {
        Src s = {hbuf(st, HE3, p, 0, 256), hbuf(st, HE3, p, 1, 256), 256, 1};
        linear_tile(lane, wid, s, W + KHI, W + KLO, 256, keyb, ringk + (size_t)slot * 64 * 256,
                    nullptr, nullptr);
      } else if (wid < 32) {
        Src s = {hbuf(st, HE3, p, 0, 256), hbuf(st, HE3, p, 1, 256), 256, 1};
        linear_tile(lane, wid - 16, s, W + VHI, W + VLO, 256, valb,
                    ringv + (size_t)slot * 64 * 256, nullptr, nullptr);
      }
      BAR();
      if (t == 20) {
        // decoder bootstrap: emb(x19) + ctx=v20, then d1,d2,d3
        if (wid < 16) {
          Src s = {xh + (size_t)19 * 6144, xl + (size_t)19 * 6144, 96, 0};
          linear_tile(lane, wid, s, W + EMHI, W + EMLO, 96, embb, nullptr, embh, embl);
        } else if (wid < 32) {
          int ib = (wid - 16) * 4;
          for (int bb = ib; bb < ib + 4; ++bb)
            for (int j = 0; j < 4; ++j) {
              int e = lane + 64 * j;
              float v = ld_sc_f32(ringv + (size_t)bb * 256 + e);  // slot 0 holds v20
              unsigned short hi, lo;
              f2hilo(v, hi, lo);
              st_sc_u16(ctxh + bb * 256 + e, hi);
              st_sc_u16(ctxl + bb * 256 + e, lo);
            }
        }
        BAR();
        if (wid < 16) {
          Src ss[3] = {{embh, embl, 256, 1},
                       {ctxh, ctxl, 256, 1},
                       {hbuf(st, HD1, q, 0, 256), hbuf(st, HD1, q, 1, 256), 256, 1}};
          lstm_tile(lane, wid, 256, 256, ss, W + D1HI, W + D1LO, 768, d1b, (float*)(st + CD1),
                    hbuf(st, HD1, p, 0, 256), hbuf(st, HD1, p, 1, 256), nullptr);
        }
        BAR();
        if (wid < 16) {
          Src ss[2] = {{hbuf(st, HD1, p, 0, 256), hbuf(st, HD1, p, 1, 256), 256, 1},
                       {hbuf(st, HD2, q, 0, 256), hbuf(st, HD2, q, 1, 256), 256, 1}};
          lstm_tile(lane, wid, 256, 256, ss, W + D2HI, W + D2LO, 512, d2b, (float*)(st + CD2),
                    hbuf(st, HD2, p, 0, 256), hbuf(st, HD2, p, 1, 256), nullptr);
        }
        BAR();
        if (wid < 5) {
          Src ss[2] = {{hbuf(st, HD2, p, 0, 256), hbuf(st, HD2, p, 1, 256), 256, 1},
                       {hbuf(st, HLAST, q, 0, 96), hbuf(st, HLAST, q, 1, 96), 96, 1}};
          lstm_tile(lane, wid, 80, 96, ss, W + D3HI, W + D3LO, 352, d3b, (float*)(st + CD3),
                    hbuf(st, HLAST, p, 0, 96), hbuf(st, HLAST, p, 1, 96), dout);
        }
        BAR();
      }
    } else {
      // ---------- phase 2 ----------
      // S1: e1 | emb | attn (all depend only on step t-1)
      if (wid < 16) {
        Src ss[2] = {{hbuf(st, HLAST, q, 0, 96), hbuf(st, HLAST, q, 1, 96), 96, 1},
                     {hbuf(st, HE1, q, 0, 256), hbuf(st, HE1, q, 1, 256), 256, 1}};
        lstm_tile(lane, wid, 256, 256, ss, W + E1HI, W + E1LO, 352, e1b, (float*)(st + CE1),
                  hbuf(st, HE1, p, 0, 256), hbuf(st, HE1, p, 1, 256), nullptr);
      } else if (wid < 32) {
        Src s = {hbuf(st, HLAST, q, 0, 96), hbuf(st, HLAST, q, 1, 96), 96, 1};
        linear_tile(lane, wid - 16, s, W + EMHI, W + EMLO, 96, embb, nullptr, embh, embl);
      } else if (wid >= 64 && wid < 96) {
        int b0 = (wid - 64) * 2;
        attn_wave(lane, b0, hbuf(st, HD2, q, 0, 256), hbuf(st, HD2, q, 1, 256), ringk, ringv,
                  ctxh, ctxl);
        attn_wave(lane, b0 + 1, hbuf(st, HD2, q, 0, 256), hbuf(st, HD2, q, 1, 256), ringk, ringv,
                  ctxh, ctxl);
      }
      BAR();
      // S2: e2 | d1
      if (wid < 16) {
        Src ss[2] = {{hbuf(st, HE1, p, 0, 256), hbuf(st, HE1, p, 1, 256), 256, 1},
                     {hbuf(st, HE2, q, 0, 256), hbuf(st, HE2, q, 1, 256), 256, 1}};
        lstm_tile(lane, wid, 256, 256, ss, W + E2HI, W + E2LO, 512, e2b, (float*)(st + CE2),
                  hbuf(st, HE2, p, 0, 256), hbuf(st, HE2, p, 1, 256), nullptr);
      } else if (wid < 32) {
        Src ss[3] = {{embh, embl, 256, 1},
                     {ctxh, ctxl, 256, 1},
                     {hbuf(st, HD1, q, 0, 256), hbuf(st, HD1, q, 1, 256), 256, 1}};
        lstm_tile(lane, wid - 16, 256, 256, ss, W + D1HI, W + D1LO, 768, d1b, (float*)(st + CD1),
                  hbuf(st, HD1, p, 0, 256), hbuf(st, HD1, p, 1, 256), nullptr);
      }
      BAR();
      // S3: e3 | d2
      if (wid < 16) {
        Src ss[2] = {{hbuf(st, HE2, p, 0, 256), hbuf(st, HE2, p, 1, 256), 256, 1},
                     {hbuf(st, HE3, q, 0, 256), hbuf(st, HE3, q, 1, 256), 256, 1}};
        lstm_tile(lane, wid, 256, 256, ss, W + E3HI, W + E3LO, 512, e3b, (float*)(st + CE3),
                  hbuf(st, HE3, p, 0, 256), hbuf(st, HE3, p, 1, 256), nullptr);
      } else if (wid < 32) {
        Src ss[2] = {{hbuf(st, HD1, p, 0, 256), hbuf(st, HD1, p, 1, 256), 256, 1},
                     {hbuf(st, HD2, q, 0, 256), hbuf(st, HD2, q, 1, 256), 256, 1}};
        lstm_tile(lane, wid - 16, 256, 256, ss, W + D2HI, W + D2LO, 512, d2b, (float*)(st + CD2),
                  hbuf(st, HD2, p, 0, 256), hbuf(st, HD2, p, 1, 256), nullptr);
      }
      BAR();
      // S4: key | val | d3 (output + last)
      if (wid < 16) {
        Src s = {hbuf(st, HE3, p, 0, 256), hbuf(st, HE3, p, 1, 256), 256, 1};
        linear_tile(lane, wid, s, W + KHI, W + KLO, 256, keyb, ringk + (size_t)slot * 64 * 256,
                    nullptr, nullptr);
      } else if (wid < 32) {
        Src s = {hbuf(st, HE3, p, 0, 256), hbuf(st, HE3, p, 1, 256), 256, 1};
        linear_tile(lane, wid - 16, s, W + VHI, W + VLO, 256, valb,
                    ringv + (size_t)slot * 64 * 256, nullptr, nullptr);
      } else if (wid < 37) {
        Src ss[2] = {{hbuf(st, HD2, p, 0, 256), hbuf(st, HD2, p, 1, 256), 256, 1},
                     {hbuf(st, HLAST, q, 0, 96), hbuf(st, HLAST, q, 1, 96), 96, 1}};
        lstm_tile(lane, wid - 32, 80, 96, ss, W + D3HI, W + D3LO, 352, d3b, (float*)(st + CD3),
                  hbuf(st, HLAST, p, 0, 96), hbuf(st, HLAST, p, 1, 96),
                  dout + (size_t)(t - 20) * 80);
      }
      BAR();
    }
  }
}

// ---------------- launch ----------------
extern "C" void kernel_launch(void* const* d_in, const int* in_sizes, int n_in, void* d_out,
                              int out_size, void* d_ws, size_t ws_size, hipStream_t stream) {
  if (ws_size < WS_NEED) return;  // insufficient scratch; fail loudly (wrong output)

  const float* x = (const float*)d_in[0];
  const float* embW = (const float*)d_in[1];
  const float* embB = (const float*)d_in[2];
  const float* e1Wih = (const float*)d_in[3];
  const float* e1Whh = (const float*)d_in[4];
  const float* e1B = (const float*)d_in[5];
  const float* e2Wih = (const float*)d_in[6];
  const float* e2Whh = (const float*)d_in[7];
  const float* e2B = (const float*)d_in[8];
  const float* e3Wih = (const float*)d_in[9];
  const float* e3Whh = (const float*)d_in[10];
  const float* e3B = (const float*)d_in[11];
  const float* d1Wih = (const float*)d_in[12];
  const float* d1Whh = (const float*)d_in[13];
  const float* d1B = (const float*)d_in[14];
  const float* d2Wih = (const float*)d_in[15];
  const float* d2Whh = (const float*)d_in[16];
  const float* d2B = (const float*)d_in[17];
  const float* d3Wih = (const float*)d_in[18];
  const float* d3Whh = (const float*)d_in[19];
  const float* d3B = (const float*)d_in[20];
  const float* keyW = (const float*)d_in[21];
  const float* keyB = (const float*)d_in[22];
  const float* valW = (const float*)d_in[23];
  const float* valB = (const float*)d_in[24];

  unsigned char* ws = (unsigned char*)d_ws;
  unsigned short* W = (unsigned short*)ws;
  float* doutf = (float*)d_out;

  auto launch_w = [&](const float* wih, int din, const float* whh, int dh, int rows, int dinp,
                      int kp, size_t offhi, size_t offlo) {
    size_t tot = (size_t)rows * kp;
    int blocks = (int)((tot + 255) / 256);
    prep_w<<<blocks, 256, 0, stream>>>(wih, din, whh, dh, rows, dinp, kp, W + offhi, W + offlo);
  };
  launch_w(e1Wih, 80, e1Whh, 256, 1024, 96, 352, E1HI, E1LO);
  launch_w(e2Wih, 256, e2Whh, 256, 1024, 256, 512, E2HI, E2LO);
  launch_w(e3Wih, 256, e3Whh, 256, 1024, 256, 512, E3HI, E3LO);
  launch_w(d1Wih, 512, d1Whh, 256, 1024, 512, 768, D1HI, D1LO);
  launch_w(d2Wih, 256, d2Whh, 256, 1024, 256, 512, D2HI, D2LO);
  launch_w(d3Wih, 256, d3Whh, 80, 320, 256, 352, D3HI, D3LO);
  launch_w(keyW, 256, nullptr, 0, 256, 256, 256, KHI, KLO);
  launch_w(valW, 256, nullptr, 0, 256, 256, 256, VHI, VLO);
  launch_w(embW, 80, nullptr, 0, 256, 96, 96, EMHI, EMLO);
  prep_x<<<(int)((XPAD_ELEMS + 255) / 256), 256, 0, stream>>>(
      x, (unsigned short*)(ws + XPAD_HI_B), (unsigned short*)(ws + XPAD_LO_B));
  hipMemsetAsync(ws + STATE_B, 0, STATE_BYTES, stream);

  void* args[] = {(void*)&e1B,  (void*)&e2B,  (void*)&e3B, (void*)&d1B, (void*)&d2B,
                  (void*)&d3B,  (void*)&embB, (void*)&keyB, (void*)&valB,
                  (void*)&doutf, (void*)&ws};
  hipLaunchCooperativeKernel((void*)seq_main, dim3(NWG), dim3(WGS), args, 0, stream);
}

// Round 5
// 43705.252 us; speedup vs baseline: 4.0447x; 4.0447x over previous
//
#include <hip/hip_runtime.h>

typedef short bf16x8 __attribute__((ext_vector_type(8)));
typedef float f32x4 __attribute__((ext_vector_type(4)));

#define DEV static __device__ __forceinline__
#define SCOPE_AGENT __HIP_MEMORY_SCOPE_AGENT

// ---------------- numeric helpers ----------------
DEV unsigned short f2bf(float f) {
  unsigned u = __float_as_uint(f);
  unsigned r = u + 0x7fffu + ((u >> 16) & 1u);
  return (unsigned short)(r >> 16);
}
DEV float bf2f(unsigned short h) { return __uint_as_float(((unsigned)h) << 16); }
DEV void f2hilo(float f, unsigned short& hi, unsigned short& lo) {
  hi = f2bf(f);
  lo = f2bf(f - bf2f(hi));
}
DEV float sigm(float x) { return 1.f / (1.f + __expf(-x)); }
DEV float tanh_(float x) {
  x = fminf(15.f, fmaxf(-15.f, x));
  float e = __expf(2.f * x);
  return (e - 1.f) / (e + 1.f);
}

// ---------------- coherent (LLC) access helpers ----------------
DEV void st_sc_u16(unsigned short* p, unsigned short v) {
  __hip_atomic_store(p, v, __ATOMIC_RELAXED, SCOPE_AGENT);
}
DEV void st_sc_f32(float* p, float v) {
  __hip_atomic_store(p, v, __ATOMIC_RELAXED, SCOPE_AGENT);
}
DEV void st_sc_u64(unsigned long long* p, unsigned long long v) {
  __hip_atomic_store(p, v, __ATOMIC_RELAXED, SCOPE_AGENT);
}
DEV unsigned long long ld_sc_u64(const unsigned long long* p) {
  return __hip_atomic_load((unsigned long long*)p, __ATOMIC_RELAXED, SCOPE_AGENT);
}
DEV unsigned ld_sc_u32(const unsigned* p) {
  return __hip_atomic_load((unsigned*)p, __ATOMIC_RELAXED, SCOPE_AGENT);
}
DEV void vm_drain() { asm volatile("s_waitcnt vmcnt(0)" ::: "memory"); }

// ---------------- workspace layout ----------------
constexpr size_t WE1 = 1024 * 352, WE2 = 1024 * 512, WE3 = 1024 * 512,
                 WD1 = 1024 * 768, WD2 = 1024 * 512, WD3 = 320 * 352,
                 WKEY = 256 * 256, WVAL = 256 * 256, WEMB = 256 * 96;
constexpr size_t E1HI = 0, E1LO = E1HI + WE1, E2HI = E1LO + WE1, E2LO = E2HI + WE2,
                 E3HI = E2LO + WE2, E3LO = E3HI + WE3, D1HI = E3LO + WE3, D1LO = D1HI + WD1,
                 D2HI = D1LO + WD1, D2LO = D2HI + WD2, D3HI = D2LO + WD2, D3LO = D3HI + WD3,
                 KHI = D3LO + WD3, KLO = KHI + WKEY, VHI = KLO + WKEY, VLO = VHI + WVAL,
                 EMHI = VLO + WVAL, EMLO = EMHI + WEMB, WTOT = EMLO + WEMB;

constexpr size_t XPAD_ELEMS = (size_t)400 * 64 * 96;
constexpr size_t XPAD_HI_B = WTOT * 2;
constexpr size_t XPAD_LO_B = XPAD_HI_B + XPAD_ELEMS * 2;
constexpr size_t STATE_B = XPAD_LO_B + XPAD_ELEMS * 2;

// state sub-offsets (bytes rel. to st = ws+STATE_B); zeroed by memset each launch
constexpr size_t H256_SZB = (size_t)2 * 2 * 64 * 256 * 2;  // [parity][hi/lo][64][256] u16
constexpr size_t HE1 = 0, HE2 = H256_SZB, HE3 = 2 * H256_SZB, HD1 = 3 * H256_SZB,
                 HD2 = 4 * H256_SZB;
constexpr size_t HLAST = 5 * H256_SZB;  // [2][2][64][96] u16
constexpr size_t HLAST_SZB = (size_t)2 * 2 * 64 * 96 * 2;
constexpr size_t BARO = HLAST + HLAST_SZB;  // flag counters
constexpr size_t STATE_BYTES = BARO + 256;

// non-zeroed extras (fully rewritten before first read, every launch)
constexpr size_t RINGK_B = STATE_B + STATE_BYTES;
constexpr size_t RING_SZ = (size_t)20 * 64 * 256 * 4;
constexpr size_t RINGV_B = RINGK_B + RING_SZ;
constexpr size_t EMBH_B = RINGV_B + RING_SZ;
constexpr size_t EMBL_B = EMBH_B + (size_t)64 * 256 * 2;
constexpr size_t CTXH_B = EMBL_B + (size_t)64 * 256 * 2;
constexpr size_t CTXL_B = CTXH_B + (size_t)64 * 256 * 2;
constexpr size_t WS_NEED = CTXL_B + (size_t)64 * 256 * 2;

// flag counter indices (16B stride to avoid line sharing)
#define IE1 0
#define IE2 1
#define IE3 2
#define IKV 3
#define IEM 4
#define IAT 5
#define ID1 6
#define ID2 7
#define ID3 8

constexpr int NWG = 31;
constexpr int WGS = 256;

// ---------------- prep kernels ----------------
__global__ void prep_w(const float* __restrict__ wih, int din, const float* __restrict__ whh,
                       int dh, int rows, int dinp, int kp, unsigned short* __restrict__ whi,
                       unsigned short* __restrict__ wlo) {
  size_t idx = (size_t)blockIdx.x * 256 + threadIdx.x;
  size_t tot = (size_t)rows * kp;
  if (idx >= tot) return;
  int j = (int)(idx / kp), k = (int)(idx % kp);
  float v = 0.f;
  if (k < dinp) {
    if (k < din) v = wih[(size_t)j * din + k];
  } else {
    int k2 = k - dinp;
    if (k2 < dh) v = whh[(size_t)j * dh + k2];
  }
  unsigned short hi, lo;
  f2hilo(v, hi, lo);
  whi[idx] = hi;
  wlo[idx] = lo;
}

__global__ void prep_x(const float* __restrict__ x, unsigned short* __restrict__ xh,
                       unsigned short* __restrict__ xl) {
  size_t idx = (size_t)blockIdx.x * 256 + threadIdx.x;
  if (idx >= XPAD_ELEMS) return;
  int t = (int)(idx / 6144), rbf = (int)(idx % 6144), b = rbf / 96, f = rbf % 96;
  float v = (f < 80) ? x[(size_t)b * 32000 + (size_t)t * 80 + f] : 0.f;
  unsigned short hi, lo;
  f2hilo(v, hi, lo);
  xh[idx] = hi;
  xl[idx] = lo;
}

// ---------------- main kernel pieces ----------------
// XOR swizzle: u16 column index c -> c ^ ((row&7)<<3). 16B-granular, keeps
// u64 writes and b128 reads aligned+contiguous; spreads fragment reads over
// all 32 LDS banks instead of 4.

// bulk pipelined coherent copy of hi+lo [64][COLS] dense planes into LDS
template <int COLS, int STRIDE>
DEV void copy_hl(unsigned short* lds, const unsigned short* hi, const unsigned short* lo,
                 int tid) {
  constexpr int CU64 = COLS / 4;  // u64 per row
  constexpr int PER = 64 * CU64;  // u64 per plane
  constexpr int TOT = PER * 2;
  constexpr int loOff = 64 * STRIDE;
  for (int base = 0; base < TOT; base += WGS * 16) {
    unsigned long long v[16];
    int dst[16];
#pragma unroll
    for (int u = 0; u < 16; u++) {
      int i = base + u * WGS + tid;
      dst[u] = -1;
      if (i < TOT) {
        int pl = (i >= PER) ? 1 : 0;
        int j = pl ? (i - PER) : i;
        int row = j / CU64, cc = j - row * CU64;
        const unsigned long long* s = (const unsigned long long*)(pl ? lo : hi);
        v[u] = ld_sc_u64(s + j);
        dst[u] = (pl ? loOff : 0) + row * STRIDE + ((cc * 4) ^ ((row & 7) << 3));
      }
    }
#pragma unroll
    for (int u = 0; u < 16; u++)
      if (dst[u] >= 0) *(unsigned long long*)(lds + dst[u]) = v[u];
  }
}

DEV void mfma3(f32x4& acc, bf16x8 ah, bf16x8 al, bf16x8 bh, bf16x8 bl) {
  acc = __builtin_amdgcn_mfma_f32_16x16x32_bf16(ah, bh, acc, 0, 0, 0);
  acc = __builtin_amdgcn_mfma_f32_16x16x32_bf16(al, bh, acc, 0, 0, 0);
  acc = __builtin_amdgcn_mfma_f32_16x16x32_bf16(ah, bl, acc, 0, 0, 0);
}

DEV void zacc44(f32x4 (&a)[4][4]) {
#pragma unroll
  for (int g = 0; g < 4; g++)
#pragma unroll
    for (int m = 0; m < 4; m++) a[g][m] = f32x4{0.f, 0.f, 0.f, 0.f};
}

// LSTM MFMA pass over K columns of LDS-staged A (accumulates into acc);
// W plain loads (L2-resident), columns kwOff..kwOff+K-1 of the weight rows.
template <int K, int STRIDE>
DEV void mfma_block(const unsigned short* lds, int lane, int ut, int H,
                    const unsigned short* __restrict__ Whi,
                    const unsigned short* __restrict__ Wlo, int Kp, int kwOff,
                    f32x4 (&acc)[4][4]) {
  const int col = lane & 15, kg = lane >> 4;
  constexpr int loOff = 64 * STRIDE;
#pragma unroll
  for (int kb = 0; kb < K; kb += 32) {
    const int ka = kb + kg * 8;
    bf16x8 ah[4], al[4];
#pragma unroll
    for (int m = 0; m < 4; m++) {
      int row = m * 16 + col;
      int off = row * STRIDE + (ka ^ ((row & 7) << 3));
      ah[m] = *(const bf16x8*)(lds + off);
      al[m] = *(const bf16x8*)(lds + loOff + off);
    }
#pragma unroll
    for (int g = 0; g < 4; g++) {
      size_t wr = (size_t)(g * H + ut * 16 + col) * Kp + kwOff + ka;
      bf16x8 bh = *(const bf16x8*)(Whi + wr);
      bf16x8 bl = *(const bf16x8*)(Wlo + wr);
#pragma unroll
      for (int m = 0; m < 4; m++) mfma3(acc[g][m], ah[m], al[m], bh, bl);
    }
  }
}

template <int K, int STRIDE>
DEV void mfma_lin(const unsigned short* lds, int lane, int jt,
                  const unsigned short* __restrict__ Whi,
                  const unsigned short* __restrict__ Wlo, int Kp, f32x4 (&acc)[4]) {
  const int col = lane & 15, kg = lane >> 4;
  constexpr int loOff = 64 * STRIDE;
#pragma unroll
  for (int kb = 0; kb < K; kb += 32) {
    const int ka = kb + kg * 8;
    size_t wr = (size_t)(jt * 16 + col) * Kp + ka;
    bf16x8 bh = *(const bf16x8*)(Whi + wr);
    bf16x8 bl = *(const bf16x8*)(Wlo + wr);
#pragma unroll
    for (int m = 0; m < 4; m++) {
      int row = m * 16 + col;
      int off = row * STRIDE + (ka ^ ((row & 7) << 3));
      bf16x8 ah = *(const bf16x8*)(lds + off);
      bf16x8 al = *(const bf16x8*)(lds + loOff + off);
      mfma3(acc[m], ah, al, bh, bl);
    }
  }
}

// cell state kept in VGPRs (wave owns its (b,u) tile for the whole kernel)
DEV void cell_update(int lane, int ut, int H, int Hpad, const float* __restrict__ bias,
                     f32x4 (&acc)[4][4], float (&c)[4][4], unsigned short* hwhi,
                     unsigned short* hwlo, float* outp) {
  const int col = lane & 15, kg = lane >> 4;
  const int u = ut * 16 + col;
  const float bi = bias[u], bff = bias[H + u], bg = bias[2 * H + u], bo = bias[3 * H + u];
#pragma unroll
  for (int m = 0; m < 4; m++)
#pragma unroll
    for (int r = 0; r < 4; r++) {
      int b = m * 16 + kg * 4 + r;
      float gi = acc[0][m][r] + bi, gf = acc[1][m][r] + bff;
      float gg = acc[2][m][r] + bg, go = acc[3][m][r] + bo;
      float cn = sigm(gf) * c[m][r] + sigm(gi) * tanh_(gg);
      float hh = sigm(go) * tanh_(cn);
      c[m][r] = cn;
      unsigned short hi, lo;
      f2hilo(hh, hi, lo);
      st_sc_u16(hwhi + b * Hpad + u, hi);
      st_sc_u16(hwlo + b * Hpad + u, lo);
      if (outp) outp[(size_t)b * 30400 + u] = hh;
    }
}

DEV void spin_ge(unsigned* c, unsigned tgt) {
  while (ld_sc_u32(c) < tgt) __builtin_amdgcn_s_sleep(1);
}

__global__ void __launch_bounds__(WGS, 1)
seq_main(const float* e1b, const float* e2b, const float* e3b, const float* d1b,
         const float* d2b, const float* d3b, const float* embb, const float* keyb,
         const float* valb, float* dout, unsigned char* ws) {
  __shared__ unsigned short lds_s[32768];  // 64 KB static
  unsigned short* lds = lds_s;

  const int wg = blockIdx.x, tid = threadIdx.x;
  const int wv = tid >> 6, lane = tid & 63;

  unsigned short* W = (unsigned short*)ws;
  const unsigned short* xh = (const unsigned short*)(ws + XPAD_HI_B);
  const unsigned short* xl = (const unsigned short*)(ws + XPAD_LO_B);
  unsigned char* st = ws + STATE_B;
  float* ringk = (float*)(ws + RINGK_B);
  float* ringv = (float*)(ws + RINGV_B);
  unsigned short* embh = (unsigned short*)(ws + EMBH_B);
  unsigned short* embl = (unsigned short*)(ws + EMBL_B);
  unsigned short* ctxh = (unsigned short*)(ws + CTXH_B);
  unsigned short* ctxl = (unsigned short*)(ws + CTXL_B);
  unsigned* cnt = (unsigned*)(st + BARO);
  unsigned *ce1 = cnt + IE1 * 4, *ce2 = cnt + IE2 * 4, *ce3 = cnt + IE3 * 4,
           *ckv = cnt + IKV * 4, *cem = cnt + IEM * 4, *cat = cnt + IAT * 4,
           *cd1 = cnt + ID1 * 4, *cd2 = cnt + ID2 * 4, *cd3 = cnt + ID3 * 4;

  auto hb = [&](size_t off, int par, int hl, int Hpad) {
    return (unsigned short*)(st + off) + (size_t)(par * 2 + hl) * 64 * Hpad;
  };
  auto bump = [&](unsigned* c) {
    if (tid == 0) __hip_atomic_fetch_add(c, 1u, __ATOMIC_RELAXED, SCOPE_AGENT);
  };

  if (wg < 4) {  // ---------------- e1 ----------------
    const int ut = wg * 4 + wv;
    float c[4][4] = {{0.f}};
    for (int t = 0; t < 400; ++t) {
      const int p = t & 1, q = p ^ 1;
      if (tid < 64) {
        if (t >= 1) spin_ge(ce1, 4u * t);
        if (t >= 2) spin_ge(ce2, 4u * (t - 1));
        if (t >= 21) spin_ge(cd3, 2u * (t - 20));
      }
      __syncthreads();
      if (t <= 20)
        copy_hl<96, 128>(lds, xh + (size_t)t * 6144, xl + (size_t)t * 6144, tid);
      else
        copy_hl<96, 128>(lds, hb(HLAST, q, 0, 96), hb(HLAST, q, 1, 96), tid);
      __syncthreads();
      f32x4 acc[4][4];
      zacc44(acc);
      mfma_block<96, 128>(lds, lane, ut, 256, W + E1HI, W + E1LO, 352, 0, acc);
      __syncthreads();
      copy_hl<256, 256>(lds, hb(HE1, q, 0, 256), hb(HE1, q, 1, 256), tid);
      __syncthreads();
      mfma_block<256, 256>(lds, lane, ut, 256, W + E1HI, W + E1LO, 352, 96, acc);
      cell_update(lane, ut, 256, 256, e1b, acc, c, hb(HE1, p, 0, 256), hb(HE1, p, 1, 256),
                  nullptr);
      vm_drain();
      __syncthreads();
      bump(ce1);
    }
  } else if (wg < 8) {  // ---------------- e2 ----------------
    const int ut = (wg - 4) * 4 + wv;
    float c[4][4] = {{0.f}};
    for (int t = 0; t < 400; ++t) {
      const int p = t & 1, q = p ^ 1;
      if (tid < 64) {
        spin_ge(ce1, 4u * (t + 1));
        if (t >= 1) spin_ge(ce2, 4u * t);
        if (t >= 2) spin_ge(ce3, 4u * (t - 1));
      }
      __syncthreads();
      copy_hl<256, 256>(lds, hb(HE1, p, 0, 256), hb(HE1, p, 1, 256), tid);
      __syncthreads();
      f32x4 acc[4][4];
      zacc44(acc);
      mfma_block<256, 256>(lds, lane, ut, 256, W + E2HI, W + E2LO, 512, 0, acc);
      __syncthreads();
      copy_hl<256, 256>(lds, hb(HE2, q, 0, 256), hb(HE2, q, 1, 256), tid);
      __syncthreads();
      mfma_block<256, 256>(lds, lane, ut, 256, W + E2HI, W + E2LO, 512, 256, acc);
      cell_update(lane, ut, 256, 256, e2b, acc, c, hb(HE2, p, 0, 256), hb(HE2, p, 1, 256),
                  nullptr);
      vm_drain();
      __syncthreads();
      bump(ce2);
    }
  } else if (wg < 12) {  // ---------------- e3 ----------------
    const int ut = (wg - 8) * 4 + wv;
    float c[4][4] = {{0.f}};
    for (int t = 0; t < 400; ++t) {
      const int p = t & 1, q = p ^ 1;
      if (tid < 64) {
        spin_ge(ce2, 4u * (t + 1));
        if (t >= 1) spin_ge(ce3, 4u * t);
        if (t >= 2) spin_ge(ckv, 4u * (t - 1));
      }
      __syncthreads();
      copy_hl<256, 256>(lds, hb(HE2, p, 0, 256), hb(HE2, p, 1, 256), tid);
      __syncthreads();
      f32x4 acc[4][4];
      zacc44(acc);
      mfma_block<256, 256>(lds, lane, ut, 256, W + E3HI, W + E3LO, 512, 0, acc);
      __syncthreads();
      copy_hl<256, 256>(lds, hb(HE3, q, 0, 256), hb(HE3, q, 1, 256), tid);
      __syncthreads();
      mfma_block<256, 256>(lds, lane, ut, 256, W + E3HI, W + E3LO, 512, 256, acc);
      cell_update(lane, ut, 256, 256, e3b, acc, c, hb(HE3, p, 0, 256), hb(HE3, p, 1, 256),
                  nullptr);
      vm_drain();
      __syncthreads();
      bump(ce3);
    }
  } else if (wg < 16) {  // ---------------- d1 ----------------
    const int ut = (wg - 12) * 4 + wv;
    float c[4][4] = {{0.f}};
    for (int t = 20; t < 400; ++t) {
      const int p = t & 1, q = p ^ 1;
      if (tid < 64) {
        spin_ge(cem, (unsigned)(t - 19));
        spin_ge(cat, 4u * (t - 19));
        if (t >= 21) spin_ge(cd1, 4u * (t - 20));
      }
      __syncthreads();
      copy_hl<256, 256>(lds, embh, embl, tid);
      __syncthreads();
      f32x4 acc[4][4];
      zacc44(acc);
      mfma_block<256, 256>(lds, lane, ut, 256, W + D1HI, W + D1LO, 768, 0, acc);
      __syncthreads();
      copy_hl<256, 256>(lds, ctxh, ctxl, tid);
      __syncthreads();
      mfma_block<256, 256>(lds, lane, ut, 256, W + D1HI, W + D1LO, 768, 256, acc);
      __syncthreads();
      copy_hl<256, 256>(lds, hb(HD1, q, 0, 256), hb(HD1, q, 1, 256), tid);
      __syncthreads();
      mfma_block<256, 256>(lds, lane, ut, 256, W + D1HI, W + D1LO, 768, 512, acc);
      cell_update(lane, ut, 256, 256, d1b, acc, c, hb(HD1, p, 0, 256), hb(HD1, p, 1, 256),
                  nullptr);
      vm_drain();
      __syncthreads();
      bump(cd1);
    }
  } else if (wg < 20) {  // ---------------- d2 ----------------
    const int ut = (wg - 16) * 4 + wv;
    float c[4][4] = {{0.f}};
    for (int t = 20; t < 400; ++t) {
      const int p = t & 1, q = p ^ 1;
      if (tid < 64) {
        spin_ge(cd1, 4u * (t - 19));
        if (t >= 21) spin_ge(cd2, 4u * (t - 20));
      }
      __syncthreads();
      copy_hl<256, 256>(lds, hb(HD1, p, 0, 256), hb(HD1, p, 1, 256), tid);
      __syncthreads();
      f32x4 acc[4][4];
      zacc44(acc);
      mfma_block<256, 256>(lds, lane, ut, 256, W + D2HI, W + D2LO, 512, 0, acc);
      __syncthreads();
      copy_hl<256, 256>(lds, hb(HD2, q, 0, 256), hb(HD2, q, 1, 256), tid);
      __syncthreads();
      mfma_block<256, 256>(lds, lane, ut, 256, W + D2HI, W + D2LO, 512, 256, acc);
      cell_update(lane, ut, 256, 256, d2b, acc, c, hb(HD2, p, 0, 256), hb(HD2, p, 1, 256),
                  nullptr);
      vm_drain();
      __syncthreads();
      bump(cd2);
    }
  } else if (wg < 22) {  // ---------------- d3 ----------------
    const int ut = (wg - 20) * 4 + wv;  // 0..7; active if <5
    float c[4][4] = {{0.f}};
    for (int t = 20; t < 400; ++t) {
      const int p = t & 1, q = p ^ 1;
      if (tid < 64) {
        spin_ge(cd2, 4u * (t - 19));
        if (t >= 21) spin_ge(cd3, 2u * (t - 20));
      }
      __syncthreads();
      copy_hl<256, 256>(lds, hb(HD2, p, 0, 256), hb(HD2, p, 1, 256), tid);
      __syncthreads();
      f32x4 acc[4][4];
      zacc44(acc);
      if (ut < 5) mfma_block<256, 256>(lds, lane, ut, 80, W + D3HI, W + D3LO, 352, 0, acc);
      __syncthreads();
      copy_hl<96, 128>(lds, hb(HLAST, q, 0, 96), hb(HLAST, q, 1, 96), tid);
      __syncthreads();
      if (ut < 5) {
        mfma_block<96, 128>(lds, lane, ut, 80, W + D3HI, W + D3LO, 352, 256, acc);
        cell_update(lane, ut, 80, 96, d3b, acc, c, hb(HLAST, p, 0, 96), hb(HLAST, p, 1, 96),
                    dout + (size_t)(t - 20) * 80);
      }
      vm_drain();
      __syncthreads();
      bump(cd3);
    }
  } else if (wg < 26) {  // ---------------- key (22,23) / val (24,25) ----------------
    const bool isKey = wg < 24;
    const unsigned short* Whi = W + (isKey ? KHI : VHI);
    const unsigned short* Wlo = W + (isKey ? KLO : VLO);
    const float* bias = isKey ? keyb : valb;
    float* ring = isKey ? ringk : ringv;
    const int jt0 = ((wg - (isKey ? 22 : 24)) * 4 + wv) * 2;
    const int col = lane & 15, kg = lane >> 4;
    for (int t = 0; t < 400; ++t) {
      const int p = t & 1;
      const int slot = t % 20;
      if (tid < 64) {
        spin_ge(ce3, 4u * (t + 1));
        if (t >= 21) spin_ge(cat, 4u * (t - 19));
      }
      __syncthreads();
      copy_hl<256, 256>(lds, hb(HE3, p, 0, 256), hb(HE3, p, 1, 256), tid);
      __syncthreads();
      float* outp = ring + (size_t)slot * 64 * 256;
#pragma unroll
      for (int tt = 0; tt < 2; ++tt) {
        int jt = jt0 + tt;
        f32x4 acc[4];
#pragma unroll
        for (int m = 0; m < 4; m++) acc[m] = f32x4{0.f, 0.f, 0.f, 0.f};
        mfma_lin<256, 256>(lds, lane, jt, Whi, Wlo, 256, acc);
        int j = jt * 16 + col;
        float bj = bias[j];
#pragma unroll
        for (int m = 0; m < 4; m++)
#pragma unroll
          for (int r = 0; r < 4; r++) {
            int b = m * 16 + kg * 4 + r;
            st_sc_f32(outp + (size_t)b * 256 + j, acc[m][r] + bj);
          }
      }
      vm_drain();
      __syncthreads();
      bump(ckv);
    }
  } else if (wg == 26) {  // ---------------- emb ----------------
    const int col = lane & 15, kg = lane >> 4;
    for (int t = 20; t < 400; ++t) {
      const int q = (t & 1) ^ 1;
      if (tid < 64) {
        if (t >= 21) spin_ge(cd3, 2u * (t - 20));
      }
      __syncthreads();
      if (t == 20)
        copy_hl<96, 128>(lds, xh + (size_t)19 * 6144, xl + (size_t)19 * 6144, tid);
      else
        copy_hl<96, 128>(lds, hb(HLAST, q, 0, 96), hb(HLAST, q, 1, 96), tid);
      __syncthreads();
#pragma unroll
      for (int tt = 0; tt < 4; ++tt) {
        int jt = wv * 4 + tt;
        f32x4 acc[4];
#pragma unroll
        for (int m = 0; m < 4; m++) acc[m] = f32x4{0.f, 0.f, 0.f, 0.f};
        mfma_lin<96, 128>(lds, lane, jt, W + EMHI, W + EMLO, 96, acc);
        int j = jt * 16 + col;
        float bj = embb[j];
#pragma unroll
        for (int m = 0; m < 4; m++)
#pragma unroll
          for (int r = 0; r < 4; r++) {
            int b = m * 16 + kg * 4 + r;
            float v = acc[m][r] + bj;
            unsigned short hi, lo;
            f2hilo(v, hi, lo);
            st_sc_u16(embh + b * 256 + j, hi);
            st_sc_u16(embl + b * 256 + j, lo);
          }
      }
      vm_drain();
      __syncthreads();
      bump(cem);
    }
  } else {  // ---------------- attn (27..30) ----------------
    const int b0 = ((wg - 27) * 4 + wv) * 4;
    for (int t = 20; t < 400; ++t) {
      const int q = (t & 1) ^ 1;
      if (t == 20) {
        if (tid < 64) spin_ge(ckv, 4u * 21);
        __syncthreads();
        // ctx := v20 (ring slot 0)
#pragma unroll
        for (int r = 0; r < 4; ++r) {
          int b = b0 + r;
          const unsigned long long* vp =
              (const unsigned long long*)(ringv + (size_t)b * 256 + lane * 4);
          unsigned long long v0 = ld_sc_u64(vp), v1 = ld_sc_u64(vp + 1);
          float f[4] = {__uint_as_float((unsigned)v0), __uint_as_float((unsigned)(v0 >> 32)),
                        __uint_as_float((unsigned)v1), __uint_as_float((unsigned)(v1 >> 32))};
          unsigned short hi[4], lo[4];
#pragma unroll
          for (int j = 0; j < 4; j++) f2hilo(f[j], hi[j], lo[j]);
          unsigned long long ph = (unsigned long long)hi[0] | ((unsigned long long)hi[1] << 16) |
                                  ((unsigned long long)hi[2] << 32) |
                                  ((unsigned long long)hi[3] << 48);
          unsigned long long pl = (unsigned long long)lo[0] | ((unsigned long long)lo[1] << 16) |
                                  ((unsigned long long)lo[2] << 32) |
                                  ((unsigned long long)lo[3] << 48);
          st_sc_u64((unsigned long long*)(ctxh + b * 256 + lane * 4), ph);
          st_sc_u64((unsigned long long*)(ctxl + b * 256 + lane * 4), pl);
        }
      } else {
        if (tid < 64) {
          spin_ge(cd2, 4u * (t - 20));
          spin_ge(ckv, 4u * t);
        }
        __syncthreads();
        const unsigned short* qh = hb(HD2, q, 0, 256);
        const unsigned short* ql = hb(HD2, q, 1, 256);
#pragma unroll
        for (int r = 0; r < 4; ++r) {
          int b = b0 + r;
          unsigned long long hq =
              ld_sc_u64((const unsigned long long*)(qh + b * 256 + lane * 4));
          unsigned long long lq =
              ld_sc_u64((const unsigned long long*)(ql + b * 256 + lane * 4));
          float qv[4];
#pragma unroll
          for (int j = 0; j < 4; j++)
            qv[j] = bf2f((unsigned short)(hq >> (16 * j))) +
                    bf2f((unsigned short)(lq >> (16 * j)));
          float s[20];
#pragma unroll
          for (int kk = 0; kk < 20; kk++) {
            const unsigned long long* kp =
                (const unsigned long long*)(ringk + ((size_t)kk * 64 + b) * 256 + lane * 4);
            unsigned long long k0 = ld_sc_u64(kp), k1 = ld_sc_u64(kp + 1);
            s[kk] = __uint_as_float((unsigned)k0) * qv[0] +
                    __uint_as_float((unsigned)(k0 >> 32)) * qv[1] +
                    __uint_as_float((unsigned)k1) * qv[2] +
                    __uint_as_float((unsigned)(k1 >> 32)) * qv[3];
          }
#pragma unroll
          for (int off = 32; off >= 1; off >>= 1)
#pragma unroll
            for (int kk = 0; kk < 20; kk++) s[kk] += __shfl_xor(s[kk], off, 64);
          float mx = s[0];
#pragma unroll
          for (int kk = 1; kk < 20; kk++) mx = fmaxf(mx, s[kk]);
          float den = 0.f;
#pragma unroll
          for (int kk = 0; kk < 20; kk++) {
            s[kk] = __expf(s[kk] - mx);
            den += s[kk];
          }
          float inv = 1.f / den;
          float a0 = 0.f, a1 = 0.f, a2 = 0.f, a3 = 0.f;
#pragma unroll
          for (int kk = 0; kk < 20; kk++) {
            const unsigned long long* vp =
                (const unsigned long long*)(ringv + ((size_t)kk * 64 + b) * 256 + lane * 4);
            unsigned long long v0 = ld_sc_u64(vp), v1 = ld_sc_u64(vp + 1);
            a0 += s[kk] * __uint_as_float((unsigned)v0);
            a1 += s[kk] * __uint_as_float((unsigned)(v0 >> 32));
            a2 += s[kk] * __uint_as_float((unsigned)v1);
            a3 += s[kk] * __uint_as_float((unsigned)(v1 >> 32));
          }
          float f[4] = {a0 * inv, a1 * inv, a2 * inv, a3 * inv};
          unsigned short hi[4], lo[4];
#pragma unroll
          for (int j = 0; j < 4; j++) f2hilo(f[j], hi[j], lo[j]);
          unsigned long long ph = (unsigned long long)hi[0] | ((unsigned long long)hi[1] << 16) |
                                  ((unsigned long long)hi[2] << 32) |
                                  ((unsigned long long)hi[3] << 48);
          unsigned long long pl = (unsigned long long)lo[0] | ((unsigned long long)lo[1] << 16) |
                                  ((unsigned long long)lo[2] << 32) |
                                  ((unsigned long long)lo[3] << 48);
          st_sc_u64((unsigned long long*)(ctxh + b * 256 + lane * 4), ph);
          st_sc_u64((unsigned long long*)(ctxl + b * 256 + lane * 4), pl);
        }
      }
      vm_drain();
      __syncthreads();
      bump(cat);
    }
  }
}

// ---------------- launch ----------------
extern "C" void kernel_launch(void* const* d_in, const int* in_sizes, int n_in, void* d_out,
                              int out_size, void* d_ws, size_t ws_size, hipStream_t stream) {
  if (ws_size < WS_NEED) return;

  const float* x = (const float*)d_in[0];
  const float* embW = (const float*)d_in[1];
  const float* embB = (const float*)d_in[2];
  const float* e1Wih = (const float*)d_in[3];
  const float* e1Whh = (const float*)d_in[4];
  const float* e1B = (const float*)d_in[5];
  const float* e2Wih = (const float*)d_in[6];
  const float* e2Whh = (const float*)d_in[7];
  const float* e2B = (const float*)d_in[8];
  const float* e3Wih = (const float*)d_in[9];
  const float* e3Whh = (const float*)d_in[10];
  const float* e3B = (const float*)d_in[11];
  const float* d1Wih = (const float*)d_in[12];
  const float* d1Whh = (const float*)d_in[13];
  const float* d1B = (const float*)d_in[14];
  const float* d2Wih = (const float*)d_in[15];
  const float* d2Whh = (const float*)d_in[16];
  const float* d2B = (const float*)d_in[17];
  const float* d3Wih = (const float*)d_in[18];
  const float* d3Whh = (const float*)d_in[19];
  const float* d3B = (const float*)d_in[20];
  const float* keyW = (const float*)d_in[21];
  const float* keyB = (const float*)d_in[22];
  const float* valW = (const float*)d_in[23];
  const float* valB = (const float*)d_in[24];

  unsigned char* ws = (unsigned char*)d_ws;
  unsigned short* W = (unsigned short*)ws;
  float* doutf = (float*)d_out;

  auto launch_w = [&](const float* wih, int din, const float* whh, int dh, int rows, int dinp,
                      int kp, size_t offhi, size_t offlo) {
    size_t tot = (size_t)rows * kp;
    int blocks = (int)((tot + 255) / 256);
    prep_w<<<blocks, 256, 0, stream>>>(wih, din, whh, dh, rows, dinp, kp, W + offhi, W + offlo);
  };
  launch_w(e1Wih, 80, e1Whh, 256, 1024, 96, 352, E1HI, E1LO);
  launch_w(e2Wih, 256, e2Whh, 256, 1024, 256, 512, E2HI, E2LO);
  launch_w(e3Wih, 256, e3Whh, 256, 1024, 256, 512, E3HI, E3LO);
  launch_w(d1Wih, 512, d1Whh, 256, 1024, 512, 768, D1HI, D1LO);
  launch_w(d2Wih, 256, d2Whh, 256, 1024, 256, 512, D2HI, D2LO);
  launch_w(d3Wih, 256, d3Whh, 80, 320, 256, 352, D3HI, D3LO);
  launch_w(keyW, 256, nullptr, 0, 256, 256, 256, KHI, KLO);
  launch_w(valW, 256, nullptr, 0, 256, 256, 256, VHI, VLO);
  launch_w(embW, 80, nullptr, 0, 256, 96, 96, EMHI, EMLO);
  prep_x<<<(int)((XPAD_ELEMS + 255) / 256), 256, 0, stream>>>(
      x, (unsigned short*)(ws + XPAD_HI_B), (unsigned short*)(ws + XPAD_LO_B));
  hipMemsetAsync(ws + STATE_B, 0, STATE_BYTES, stream);

  seq_main<<<dim3(NWG), dim3(WGS), 0, stream>>>(e1B, e2B, e3B, d1B, d2B, d3B, embB, keyB,
                                                valB, doutf, ws);
}

// Round 6
// 23846.255 us; speedup vs baseline: 7.4131x; 1.8328x over previous
//
#include <hip/hip_runtime.h>

typedef short bf16x8 __attribute__((ext_vector_type(8)));
typedef float f32x4 __attribute__((ext_vector_type(4)));

#define DEV static __device__ __forceinline__
#define SCOPE_AGENT __HIP_MEMORY_SCOPE_AGENT

// ---------------- numeric helpers ----------------
DEV unsigned short f2bf(float f) {
  unsigned u = __float_as_uint(f);
  unsigned r = u + 0x7fffu + ((u >> 16) & 1u);
  return (unsigned short)(r >> 16);
}
DEV float bf2f(unsigned short h) { return __uint_as_float(((unsigned)h) << 16); }
DEV void f2hilo(float f, unsigned short& hi, unsigned short& lo) {
  hi = f2bf(f);
  lo = f2bf(f - bf2f(hi));
}
DEV float sigm(float x) { return 1.f / (1.f + __expf(-x)); }
DEV float tanh_(float x) {
  x = fminf(15.f, fmaxf(-15.f, x));
  float e = __expf(2.f * x);
  return (e - 1.f) / (e + 1.f);
}

// ---------------- coherent (LLC) access helpers ----------------
DEV void st_sc_u16(unsigned short* p, unsigned short v) {
  __hip_atomic_store(p, v, __ATOMIC_RELAXED, SCOPE_AGENT);
}
DEV void st_sc_f32(float* p, float v) {
  __hip_atomic_store(p, v, __ATOMIC_RELAXED, SCOPE_AGENT);
}
DEV void st_sc_u64(unsigned long long* p, unsigned long long v) {
  __hip_atomic_store(p, v, __ATOMIC_RELAXED, SCOPE_AGENT);
}
DEV unsigned long long ld_sc_u64(const unsigned long long* p) {
  return __hip_atomic_load((unsigned long long*)p, __ATOMIC_RELAXED, SCOPE_AGENT);
}
DEV unsigned ld_sc_u32(const unsigned* p) {
  return __hip_atomic_load((unsigned*)p, __ATOMIC_RELAXED, SCOPE_AGENT);
}
DEV void vm_drain() { asm volatile("s_waitcnt vmcnt(0)" ::: "memory"); }

// ---------------- workspace layout ----------------
constexpr size_t WE1 = 1024 * 352, WE2 = 1024 * 512, WE3 = 1024 * 512,
                 WD1 = 1024 * 768, WD2 = 1024 * 512, WD3 = 320 * 352,
                 WKEY = 256 * 256, WVAL = 256 * 256, WEMB = 256 * 96;
constexpr size_t E1HI = 0, E1LO = E1HI + WE1, E2HI = E1LO + WE1, E2LO = E2HI + WE2,
                 E3HI = E2LO + WE2, E3LO = E3HI + WE3, D1HI = E3LO + WE3, D1LO = D1HI + WD1,
                 D2HI = D1LO + WD1, D2LO = D2HI + WD2, D3HI = D2LO + WD2, D3LO = D3HI + WD3,
                 KHI = D3LO + WD3, KLO = KHI + WKEY, VHI = KLO + WKEY, VLO = VHI + WVAL,
                 EMHI = VLO + WVAL, EMLO = EMHI + WEMB, WTOT = EMLO + WEMB;

constexpr size_t XPAD_ELEMS = (size_t)400 * 64 * 96;
constexpr size_t XPAD_HI_B = WTOT * 2;
constexpr size_t XPAD_LO_B = XPAD_HI_B + XPAD_ELEMS * 2;
constexpr size_t STATE_B = XPAD_LO_B + XPAD_ELEMS * 2;

// state (zeroed each launch): h buffers + flag arrays
constexpr size_t H256_SZB = (size_t)2 * 2 * 64 * 256 * 2;  // [parity][hi/lo][64][256] u16
constexpr size_t HE1 = 0, HE2 = H256_SZB, HE3 = 2 * H256_SZB, HD1 = 3 * H256_SZB,
                 HD2 = 4 * H256_SZB;
constexpr size_t HLAST = 5 * H256_SZB;  // [2][2][64][96] u16
constexpr size_t HLAST_SZB = (size_t)2 * 2 * 64 * 96 * 2;
constexpr size_t BARO = HLAST + HLAST_SZB;  // cnt[9][400] u32
constexpr size_t STATE_BYTES = BARO + 9 * 400 * 4 + 64;

// non-zeroed (fully rewritten before first read each launch)
constexpr size_t RINGK_B = STATE_B + STATE_BYTES;
constexpr size_t RING_SZ = (size_t)22 * 64 * 256 * 4;  // 22 slots: kv(t) only WARs attn(t-2)
constexpr size_t RINGV_B = RINGK_B + RING_SZ;
constexpr size_t EMBH_B = RINGV_B + RING_SZ;
constexpr size_t EMBL_B = EMBH_B + (size_t)64 * 256 * 2;
constexpr size_t CTXH_B = EMBL_B + (size_t)64 * 256 * 2;
constexpr size_t CTXL_B = CTXH_B + (size_t)64 * 256 * 2;
constexpr size_t WS_NEED = CTXL_B + (size_t)64 * 256 * 2;

// layer flag ids; cnt[l][t] counts WGs of layer l done with step t
#define LE1 0
#define LE2 1
#define LE3 2
#define LKV 3
#define LEM 4
#define LAT 5
#define LD1 6
#define LD2 7
#define LD3 8
// targets: e1/e2/e3: 8, kv: 4, em: 1, at: 16, d1/d2: 8, d3: 3

constexpr int NWG = 64;
constexpr int WGS = 256;

// ---------------- prep kernels ----------------
__global__ void prep_w(const float* __restrict__ wih, int din, const float* __restrict__ whh,
                       int dh, int rows, int dinp, int kp, unsigned short* __restrict__ whi,
                       unsigned short* __restrict__ wlo) {
  size_t idx = (size_t)blockIdx.x * 256 + threadIdx.x;
  size_t tot = (size_t)rows * kp;
  if (idx >= tot) return;
  int j = (int)(idx / kp), k = (int)(idx % kp);
  float v = 0.f;
  if (k < dinp) {
    if (k < din) v = wih[(size_t)j * din + k];
  } else {
    int k2 = k - dinp;
    if (k2 < dh) v = whh[(size_t)j * dh + k2];
  }
  unsigned short hi, lo;
  f2hilo(v, hi, lo);
  whi[idx] = hi;
  wlo[idx] = lo;
}

__global__ void prep_x(const float* __restrict__ x, unsigned short* __restrict__ xh,
                       unsigned short* __restrict__ xl) {
  size_t idx = (size_t)blockIdx.x * 256 + threadIdx.x;
  if (idx >= XPAD_ELEMS) return;
  int t = (int)(idx / 6144), rbf = (int)(idx % 6144), b = rbf / 96, f = rbf % 96;
  float v = (f < 80) ? x[(size_t)b * 32000 + (size_t)t * 80 + f] : 0.f;
  unsigned short hi, lo;
  f2hilo(v, hi, lo);
  xh[idx] = hi;
  xl[idx] = lo;
}

// ---------------- main kernel pieces ----------------
// LDS staging with 16B XOR swizzle: u16 col c -> c ^ ((row&7)<<3)

template <int COLS, int STRIDE>
DEV void copy_hl(unsigned short* lds, const unsigned short* hi, const unsigned short* lo,
                 int tid) {
  constexpr int CU64 = COLS / 4;
  constexpr int PER = 64 * CU64;
  constexpr int TOT = PER * 2;
  constexpr int loOff = 64 * STRIDE;
  for (int base = 0; base < TOT; base += WGS * 16) {
    unsigned long long v[16];
    int dst[16];
#pragma unroll
    for (int u = 0; u < 16; u++) {
      int i = base + u * WGS + tid;
      dst[u] = -1;
      if (i < TOT) {
        int pl = (i >= PER) ? 1 : 0;
        int j = pl ? (i - PER) : i;
        int row = j / CU64, cc = j - row * CU64;
        const unsigned long long* s = (const unsigned long long*)(pl ? lo : hi);
        v[u] = ld_sc_u64(s + j);
        dst[u] = (pl ? loOff : 0) + row * STRIDE + ((cc * 4) ^ ((row & 7) << 3));
      }
    }
#pragma unroll
    for (int u = 0; u < 16; u++)
      if (dst[u] >= 0) *(unsigned long long*)(lds + dst[u]) = v[u];
  }
}

DEV void mfma3(f32x4& acc, bf16x8 ah, bf16x8 al, bf16x8 bh, bf16x8 bl) {
  acc = __builtin_amdgcn_mfma_f32_16x16x32_bf16(ah, bh, acc, 0, 0, 0);
  acc = __builtin_amdgcn_mfma_f32_16x16x32_bf16(al, bh, acc, 0, 0, 0);
  acc = __builtin_amdgcn_mfma_f32_16x16x32_bf16(ah, bl, acc, 0, 0, 0);
}

DEV void zacc44(f32x4 (&a)[4][4]) {
#pragma unroll
  for (int g = 0; g < 4; g++)
#pragma unroll
    for (int m = 0; m < 4; m++) a[g][m] = f32x4{0.f, 0.f, 0.f, 0.f};
}

// MFMA over kb index range [kbLo,kbHi) of the staged chunk (K-split support)
template <int STRIDE>
DEV void mfma_range(const unsigned short* lds, int lane, int ut, int H,
                    const unsigned short* __restrict__ Whi,
                    const unsigned short* __restrict__ Wlo, int Kp, int kwOff, int kbLo,
                    int kbHi, f32x4 (&acc)[4][4]) {
  const int col = lane & 15, kg = lane >> 4;
  constexpr int loOff = 64 * STRIDE;
  for (int kb = kbLo; kb < kbHi; kb++) {
    const int ka = kb * 32 + kg * 8;
    bf16x8 ah[4], al[4];
#pragma unroll
    for (int m = 0; m < 4; m++) {
      int row = m * 16 + col;
      int off = row * STRIDE + (ka ^ ((row & 7) << 3));
      ah[m] = *(const bf16x8*)(lds + off);
      al[m] = *(const bf16x8*)(lds + loOff + off);
    }
#pragma unroll
    for (int g = 0; g < 4; g++) {
      size_t wr = (size_t)(g * H + ut * 16 + col) * Kp + kwOff + ka;
      bf16x8 bh = *(const bf16x8*)(Whi + wr);
      bf16x8 bl = *(const bf16x8*)(Wlo + wr);
#pragma unroll
      for (int m = 0; m < 4; m++) mfma3(acc[g][m], ah[m], al[m], bh, bl);
    }
  }
}

// one staged chunk: barrier, copy, barrier, half-K MFMA
template <int COLS, int STRIDE>
DEV void chunk_pass(unsigned short* lds, const unsigned short* hi, const unsigned short* lo,
                    int tid, int lane, int ut, int utActive, int H,
                    const unsigned short* __restrict__ Whi,
                    const unsigned short* __restrict__ Wlo, int Kp, int kwOff, int half,
                    f32x4 (&acc)[4][4]) {
  __syncthreads();  // previous LDS consumers done
  copy_hl<COLS, STRIDE>(lds, hi, lo, tid);
  __syncthreads();
  constexpr int NKB = COLS / 32;
  const int lo_kb = half ? (NKB + 1) / 2 : 0;
  const int hi_kb = half ? NKB : (NKB + 1) / 2;
  if (utActive) mfma_range<STRIDE>(lds, lane, ut, H, Whi, Wlo, Kp, kwOff, lo_kb, hi_kb, acc);
}

// combine the two K-halves: half1 writes partials to LDS, half0 adds
DEV void reduce_pair(unsigned short* lds, int lane, int pair, int half, f32x4 (&acc)[4][4]) {
  float* red = (float*)lds;
  const int base = (pair * 64 + lane) * 68;  // stride 68 f32 -> banks spread
  __syncthreads();
  if (half) {
#pragma unroll
    for (int g = 0; g < 4; g++)
#pragma unroll
      for (int m = 0; m < 4; m++)
#pragma unroll
        for (int r = 0; r < 4; r++) red[base + (g * 4 + m) * 4 + r] = acc[g][m][r];
  }
  __syncthreads();
  if (!half) {
#pragma unroll
    for (int g = 0; g < 4; g++)
#pragma unroll
      for (int m = 0; m < 4; m++)
#pragma unroll
        for (int r = 0; r < 4; r++) acc[g][m][r] += red[base + (g * 4 + m) * 4 + r];
  }
}

DEV void cell_update(int lane, int ut, int H, int Hpad, const float* __restrict__ bias,
                     f32x4 (&acc)[4][4], float (&c)[4][4], unsigned short* hwhi,
                     unsigned short* hwlo, float* outp) {
  const int col = lane & 15, kg = lane >> 4;
  const int u = ut * 16 + col;
  const float bi = bias[u], bff = bias[H + u], bg = bias[2 * H + u], bo = bias[3 * H + u];
#pragma unroll
  for (int m = 0; m < 4; m++)
#pragma unroll
    for (int r = 0; r < 4; r++) {
      int b = m * 16 + kg * 4 + r;
      float gi = acc[0][m][r] + bi, gf = acc[1][m][r] + bff;
      float gg = acc[2][m][r] + bg, go = acc[3][m][r] + bo;
      float cn = sigm(gf) * c[m][r] + sigm(gi) * tanh_(gg);
      float hh = sigm(go) * tanh_(cn);
      c[m][r] = cn;
      unsigned short hi, lo;
      f2hilo(hh, hi, lo);
      st_sc_u16(hwhi + b * Hpad + u, hi);
      st_sc_u16(hwlo + b * Hpad + u, lo);
      if (outp) outp[(size_t)b * 30400 + u] = hh;
    }
}

// linear (key/val/emb): full-K per wave
template <int K, int STRIDE>
DEV void mfma_lin(const unsigned short* lds, int lane, int jt,
                  const unsigned short* __restrict__ Whi,
                  const unsigned short* __restrict__ Wlo, int Kp, f32x4 (&acc)[4]) {
  const int col = lane & 15, kg = lane >> 4;
  constexpr int loOff = 64 * STRIDE;
#pragma unroll
  for (int kb = 0; kb < K; kb += 32) {
    const int ka = kb + kg * 8;
    size_t wr = (size_t)(jt * 16 + col) * Kp + ka;
    bf16x8 bh = *(const bf16x8*)(Whi + wr);
    bf16x8 bl = *(const bf16x8*)(Wlo + wr);
#pragma unroll
    for (int m = 0; m < 4; m++) {
      int row = m * 16 + col;
      int off = row * STRIDE + (ka ^ ((row & 7) << 3));
      bf16x8 ah = *(const bf16x8*)(lds + off);
      bf16x8 al = *(const bf16x8*)(lds + loOff + off);
      mfma3(acc[m], ah, al, bh, bl);
    }
  }
}

// up to 3 flag waits; null ptr = skip. Loads issued together, then checked.
DEV void spin3(const unsigned* p0, unsigned t0, const unsigned* p1, unsigned t1,
               const unsigned* p2, unsigned t2) {
  for (;;) {
    unsigned a = p0 ? ld_sc_u32(p0) : 0xFFFFFFFFu;
    unsigned b = p1 ? ld_sc_u32(p1) : 0xFFFFFFFFu;
    unsigned c = p2 ? ld_sc_u32(p2) : 0xFFFFFFFFu;
    if (a >= t0 && b >= t1 && c >= t2) return;
    __builtin_amdgcn_s_sleep(1);
  }
}

// WAR/RAW audit (why these spins suffice):
//  HE1[p] by e1(t): readers e1(t-1){ce1[t-1]}, e2(t-2){ce2[t-2]}.
//  HE2[p] by e2(t): readers e2(t-1){ce2[t-1]}, e3(t-2){ce3[t-2]}.
//  HE3[p] by e3(t): readers e3(t-1){ce3[t-1]}, kv(t-2){ckv[t-2]}.
//  HD1[p] by d1(t): readers d1(t-1){cd1[t-1]}, d2(t-2){via cat[t]<-attn(t)<-cd2[t-1]}.
//  HD2[p] by d2(t): readers d2(t-1){cd2[t-1]}, attn(t-1)+d3(t-2){via cd1[t]/cem[t] chains}.
//  HLAST[p] by d3(t): readers d3(t-1){cd3[t-1]}, e1(t-1)/em(t-1){via cd2[t] chain}.
//  emb by em(t), ctx by attn(t): reader d1(t-1){cd1[t-1]}.
//  ring slot t%22 by kv(t): reader attn(t-2){cat[t-2]}.
__global__ void __launch_bounds__(WGS, 1)
seq_main(const float* e1b, const float* e2b, const float* e3b, const float* d1b,
         const float* d2b, const float* d3b, const float* embb, const float* keyb,
         const float* valb, float* dout, unsigned char* ws) {
  __shared__ unsigned short lds_s[32768];  // 64 KB
  unsigned short* lds = lds_s;

  const int wg = blockIdx.x, tid = threadIdx.x;
  const int wv = tid >> 6, lane = tid & 63;
  const int pair = wv >> 1, half = wv & 1;

  unsigned short* W = (unsigned short*)ws;
  const unsigned short* xh = (const unsigned short*)(ws + XPAD_HI_B);
  const unsigned short* xl = (const unsigned short*)(ws + XPAD_LO_B);
  unsigned char* st = ws + STATE_B;
  float* ringk = (float*)(ws + RINGK_B);
  float* ringv = (float*)(ws + RINGV_B);
  unsigned short* embh = (unsigned short*)(ws + EMBH_B);
  unsigned short* embl = (unsigned short*)(ws + EMBL_B);
  unsigned short* ctxh = (unsigned short*)(ws + CTXH_B);
  unsigned short* ctxl = (unsigned short*)(ws + CTXL_B);
  unsigned* C = (unsigned*)(st + BARO);
  auto CNT = [&](int l, int tt) { return C + l * 400 + tt; };

  auto hb = [&](size_t off, int par, int hl, int Hpad) {
    return (unsigned short*)(st + off) + (size_t)(par * 2 + hl) * 64 * Hpad;
  };
  auto bump = [&](int l, int tt) {
    if (tid == 0) __hip_atomic_fetch_add(CNT(l, tt), 1u, __ATOMIC_RELAXED, SCOPE_AGENT);
  };

  if (wg < 8) {  // ------------- e1: 8 WGs, 2 ut/WG, K-split 2 -------------
    const int ut = wg * 2 + pair;
    float c[4][4] = {{0.f}};
    for (int t = 0; t < 400; ++t) {
      const int p = t & 1, q = p ^ 1;
      if (tid == 0)
        spin3(t >= 1 ? CNT(LE1, t - 1) : nullptr, 8, t >= 2 ? CNT(LE2, t - 2) : nullptr, 8,
              t >= 21 ? CNT(LD3, t - 1) : nullptr, 3);
      __syncthreads();
      f32x4 acc[4][4];
      zacc44(acc);
      if (t <= 20)
        chunk_pass<96, 128>(lds, xh + (size_t)t * 6144, xl + (size_t)t * 6144, tid, lane, ut, 1,
                            256, W + E1HI, W + E1LO, 352, 0, half, acc);
      else
        chunk_pass<96, 128>(lds, hb(HLAST, q, 0, 96), hb(HLAST, q, 1, 96), tid, lane, ut, 1,
                            256, W + E1HI, W + E1LO, 352, 0, half, acc);
      chunk_pass<256, 256>(lds, hb(HE1, q, 0, 256), hb(HE1, q, 1, 256), tid, lane, ut, 1, 256,
                           W + E1HI, W + E1LO, 352, 96, half, acc);
      reduce_pair(lds, lane, pair, half, acc);
      if (!half)
        cell_update(lane, ut, 256, 256, e1b, acc, c, hb(HE1, p, 0, 256), hb(HE1, p, 1, 256),
                    nullptr);
      vm_drain();
      __syncthreads();
      bump(LE1, t);
    }
  } else if (wg < 16) {  // ------------- e2 -------------
    const int ut = (wg - 8) * 2 + pair;
    float c[4][4] = {{0.f}};
    for (int t = 0; t < 400; ++t) {
      const int p = t & 1, q = p ^ 1;
      if (tid == 0)
        spin3(CNT(LE1, t), 8, t >= 1 ? CNT(LE2, t - 1) : nullptr, 8,
              t >= 2 ? CNT(LE3, t - 2) : nullptr, 8);
      __syncthreads();
      f32x4 acc[4][4];
      zacc44(acc);
      chunk_pass<256, 256>(lds, hb(HE1, p, 0, 256), hb(HE1, p, 1, 256), tid, lane, ut, 1, 256,
                           W + E2HI, W + E2LO, 512, 0, half, acc);
      chunk_pass<256, 256>(lds, hb(HE2, q, 0, 256), hb(HE2, q, 1, 256), tid, lane, ut, 1, 256,
                           W + E2HI, W + E2LO, 512, 256, half, acc);
      reduce_pair(lds, lane, pair, half, acc);
      if (!half)
        cell_update(lane, ut, 256, 256, e2b, acc, c, hb(HE2, p, 0, 256), hb(HE2, p, 1, 256),
                    nullptr);
      vm_drain();
      __syncthreads();
      bump(LE2, t);
    }
  } else if (wg < 24) {  // ------------- e3 -------------
    const int ut = (wg - 16) * 2 + pair;
    float c[4][4] = {{0.f}};
    for (int t = 0; t < 400; ++t) {
      const int p = t & 1, q = p ^ 1;
      if (tid == 0)
        spin3(CNT(LE2, t), 8, t >= 1 ? CNT(LE3, t - 1) : nullptr, 8,
              t >= 2 ? CNT(LKV, t - 2) : nullptr, 4);
      __syncthreads();
      f32x4 acc[4][4];
      zacc44(acc);
      chunk_pass<256, 256>(lds, hb(HE2, p, 0, 256), hb(HE2, p, 1, 256), tid, lane, ut, 1, 256,
                           W + E3HI, W + E3LO, 512, 0, half, acc);
      chunk_pass<256, 256>(lds, hb(HE3, q, 0, 256), hb(HE3, q, 1, 256), tid, lane, ut, 1, 256,
                           W + E3HI, W + E3LO, 512, 256, half, acc);
      reduce_pair(lds, lane, pair, half, acc);
      if (!half)
        cell_update(lane, ut, 256, 256, e3b, acc, c, hb(HE3, p, 0, 256), hb(HE3, p, 1, 256),
                    nullptr);
      vm_drain();
      __syncthreads();
      bump(LE3, t);
    }
  } else if (wg < 28) {  // ------------- kv: 4 WGs, key+val jt per wave -------------
    const int jt = (wg - 24) * 4 + wv;
    const int col = lane & 15, kg = lane >> 4;
    for (int t = 0; t < 400; ++t) {
      const int p = t & 1;
      const int slot = t % 22;
      if (tid == 0)
        spin3(CNT(LE3, t), 8, t >= 22 ? CNT(LAT, t - 2) : nullptr, 16, nullptr, 0);
      __syncthreads();
      copy_hl<256, 256>(lds, hb(HE3, p, 0, 256), hb(HE3, p, 1, 256), tid);
      __syncthreads();
#pragma unroll
      for (int kvh = 0; kvh < 2; ++kvh) {
        const unsigned short* Whi = W + (kvh ? VHI : KHI);
        const unsigned short* Wlo = W + (kvh ? VLO : KLO);
        const float* bias = kvh ? valb : keyb;
        float* outp = (kvh ? ringv : ringk) + (size_t)slot * 64 * 256;
        f32x4 acc[4];
#pragma unroll
        for (int m = 0; m < 4; m++) acc[m] = f32x4{0.f, 0.f, 0.f, 0.f};
        mfma_lin<256, 256>(lds, lane, jt, Whi, Wlo, 256, acc);
        int j = jt * 16 + col;
        float bj = bias[j];
#pragma unroll
        for (int m = 0; m < 4; m++)
#pragma unroll
          for (int r = 0; r < 4; r++) {
            int b = m * 16 + kg * 4 + r;
            st_sc_f32(outp + (size_t)b * 256 + j, acc[m][r] + bj);
          }
      }
      vm_drain();
      __syncthreads();
      bump(LKV, t);
    }
  } else if (wg == 28) {  // ------------- emb: 1 WG -------------
    const int col = lane & 15, kg = lane >> 4;
    for (int t = 20; t < 400; ++t) {
      const int q = (t & 1) ^ 1;
      if (tid == 0 && t >= 21)
        spin3(CNT(LD3, t - 1), 3, CNT(LD1, t - 1), 8, nullptr, 0);
      __syncthreads();
      if (t == 20)
        copy_hl<96, 128>(lds, xh + (size_t)19 * 6144, xl + (size_t)19 * 6144, tid);
      else
        copy_hl<96, 128>(lds, hb(HLAST, q, 0, 96), hb(HLAST, q, 1, 96), tid);
      __syncthreads();
#pragma unroll
      for (int tt = 0; tt < 4; ++tt) {
        int jt = wv * 4 + tt;
        f32x4 acc[4];
#pragma unroll
        for (int m = 0; m < 4; m++) acc[m] = f32x4{0.f, 0.f, 0.f, 0.f};
        mfma_lin<96, 128>(lds, lane, jt, W + EMHI, W + EMLO, 96, acc);
        int j = jt * 16 + col;
        float bj = embb[j];
#pragma unroll
        for (int m = 0; m < 4; m++)
#pragma unroll
          for (int r = 0; r < 4; r++) {
            int b = m * 16 + kg * 4 + r;
            float v = acc[m][r] + bj;
            unsigned short hi, lo;
            f2hilo(v, hi, lo);
            st_sc_u16(embh + b * 256 + j, hi);
            st_sc_u16(embl + b * 256 + j, lo);
          }
      }
      vm_drain();
      __syncthreads();
      bump(LEM, t);
    }
  } else if (wg < 45) {  // ------------- attn: 16 WGs, 1 row/wave -------------
    const int b = (wg - 29) * 4 + wv;
    for (int t = 20; t < 400; ++t) {
      const int q = (t & 1) ^ 1;
      if (t == 20) {
        if (tid == 0) spin3(CNT(LKV, 20), 4, nullptr, 0, nullptr, 0);
        __syncthreads();
        // ctx := v20 (ring slot 20)
        const unsigned long long* vp =
            (const unsigned long long*)(ringv + ((size_t)20 * 64 + b) * 256 + lane * 4);
        unsigned long long v0 = ld_sc_u64(vp), v1 = ld_sc_u64(vp + 1);
        float f[4] = {__uint_as_float((unsigned)v0), __uint_as_float((unsigned)(v0 >> 32)),
                      __uint_as_float((unsigned)v1), __uint_as_float((unsigned)(v1 >> 32))};
        unsigned short hi[4], lo[4];
#pragma unroll
        for (int j = 0; j < 4; j++) f2hilo(f[j], hi[j], lo[j]);
        unsigned long long ph = (unsigned long long)hi[0] | ((unsigned long long)hi[1] << 16) |
                                ((unsigned long long)hi[2] << 32) |
                                ((unsigned long long)hi[3] << 48);
        unsigned long long pl = (unsigned long long)lo[0] | ((unsigned long long)lo[1] << 16) |
                                ((unsigned long long)lo[2] << 32) |
                                ((unsigned long long)lo[3] << 48);
        st_sc_u64((unsigned long long*)(ctxh + b * 256 + lane * 4), ph);
        st_sc_u64((unsigned long long*)(ctxl + b * 256 + lane * 4), pl);
      } else {
        if (tid == 0)
          spin3(CNT(LKV, t - 1), 4, CNT(LD2, t - 1), 8, CNT(LD1, t - 1), 8);
        __syncthreads();
        const unsigned short* qh = hb(HD2, q, 0, 256);
        const unsigned short* ql = hb(HD2, q, 1, 256);
        unsigned long long hq = ld_sc_u64((const unsigned long long*)(qh + b * 256 + lane * 4));
        unsigned long long lq = ld_sc_u64((const unsigned long long*)(ql + b * 256 + lane * 4));
        float qv[4];
#pragma unroll
        for (int j = 0; j < 4; j++)
          qv[j] = bf2f((unsigned short)(hq >> (16 * j))) + bf2f((unsigned short)(lq >> (16 * j)));
        float s[20];
#pragma unroll
        for (int i = 0; i < 20; i++) {
          int slot = (t - 20 + i) % 22;
          const unsigned long long* kp =
              (const unsigned long long*)(ringk + ((size_t)slot * 64 + b) * 256 + lane * 4);
          unsigned long long k0 = ld_sc_u64(kp), k1 = ld_sc_u64(kp + 1);
          s[i] = __uint_as_float((unsigned)k0) * qv[0] +
                 __uint_as_float((unsigned)(k0 >> 32)) * qv[1] +
                 __uint_as_float((unsigned)k1) * qv[2] +
                 __uint_as_float((unsigned)(k1 >> 32)) * qv[3];
        }
#pragma unroll
        for (int off = 32; off >= 1; off >>= 1)
#pragma unroll
          for (int i = 0; i < 20; i++) s[i] += __shfl_xor(s[i], off, 64);
        float mx = s[0];
#pragma unroll
        for (int i = 1; i < 20; i++) mx = fmaxf(mx, s[i]);
        float den = 0.f;
#pragma unroll
        for (int i = 0; i < 20; i++) {
          s[i] = __expf(s[i] - mx);
          den += s[i];
        }
        float inv = 1.f / den;
        float a0 = 0.f, a1 = 0.f, a2 = 0.f, a3 = 0.f;
#pragma unroll
        for (int i = 0; i < 20; i++) {
          int slot = (t - 20 + i) % 22;
          const unsigned long long* vp =
              (const unsigned long long*)(ringv + ((size_t)slot * 64 + b) * 256 + lane * 4);
          unsigned long long v0 = ld_sc_u64(vp), v1 = ld_sc_u64(vp + 1);
          a0 += s[i] * __uint_as_float((unsigned)v0);
          a1 += s[i] * __uint_as_float((unsigned)(v0 >> 32));
          a2 += s[i] * __uint_as_float((unsigned)v1);
          a3 += s[i] * __uint_as_float((unsigned)(v1 >> 32));
        }
        float f[4] = {a0 * inv, a1 * inv, a2 * inv, a3 * inv};
        unsigned short hi[4], lo[4];
#pragma unroll
        for (int j = 0; j < 4; j++) f2hilo(f[j], hi[j], lo[j]);
        unsigned long long ph = (unsigned long long)hi[0] | ((unsigned long long)hi[1] << 16) |
                                ((unsigned long long)hi[2] << 32) |
                                ((unsigned long long)hi[3] << 48);
        unsigned long long pl = (unsigned long long)lo[0] | ((unsigned long long)lo[1] << 16) |
                                ((unsigned long long)lo[2] << 32) |
                                ((unsigned long long)lo[3] << 48);
        st_sc_u64((unsigned long long*)(ctxh + b * 256 + lane * 4), ph);
        st_sc_u64((unsigned long long*)(ctxl + b * 256 + lane * 4), pl);
      }
      vm_drain();
      __syncthreads();
      bump(LAT, t);
    }
  } else if (wg < 53) {  // ------------- d1 -------------
    const int ut = (wg - 45) * 2 + pair;
    float c[4][4] = {{0.f}};
    for (int t = 20; t < 400; ++t) {
      const int p = t & 1, q = p ^ 1;
      if (tid == 0)
        spin3(CNT(LEM, t), 1, CNT(LAT, t), 16, t >= 21 ? CNT(LD1, t - 1) : nullptr, 8);
      __syncthreads();
      f32x4 acc[4][4];
      zacc44(acc);
      chunk_pass<256, 256>(lds, embh, embl, tid, lane, ut, 1, 256, W + D1HI, W + D1LO, 768, 0,
                           half, acc);
      chunk_pass<256, 256>(lds, ctxh, ctxl, tid, lane, ut, 1, 256, W + D1HI, W + D1LO, 768, 256,
                           half, acc);
      chunk_pass<256, 256>(lds, hb(HD1, q, 0, 256), hb(HD1, q, 1, 256), tid, lane, ut, 1, 256,
                           W + D1HI, W + D1LO, 768, 512, half, acc);
      reduce_pair(lds, lane, pair, half, acc);
      if (!half)
        cell_update(lane, ut, 256, 256, d1b, acc, c, hb(HD1, p, 0, 256), hb(HD1, p, 1, 256),
                    nullptr);
      vm_drain();
      __syncthreads();
      bump(LD1, t);
    }
  } else if (wg < 61) {  // ------------- d2 -------------
    const int ut = (wg - 53) * 2 + pair;
    float c[4][4] = {{0.f}};
    for (int t = 20; t < 400; ++t) {
      const int p = t & 1, q = p ^ 1;
      if (tid == 0)
        spin3(CNT(LD1, t), 8, t >= 21 ? CNT(LD2, t - 1) : nullptr, 8, nullptr, 0);
      __syncthreads();
      f32x4 acc[4][4];
      zacc44(acc);
      chunk_pass<256, 256>(lds, hb(HD1, p, 0, 256), hb(HD1, p, 1, 256), tid, lane, ut, 1, 256,
                           W + D2HI, W + D2LO, 512, 0, half, acc);
      chunk_pass<256, 256>(lds, hb(HD2, q, 0, 256), hb(HD2, q, 1, 256), tid, lane, ut, 1, 256,
                           W + D2HI, W + D2LO, 512, 256, half, acc);
      reduce_pair(lds, lane, pair, half, acc);
      if (!half)
        cell_update(lane, ut, 256, 256, d2b, acc, c, hb(HD2, p, 0, 256), hb(HD2, p, 1, 256),
                    nullptr);
      vm_drain();
      __syncthreads();
      bump(LD2, t);
    }
  } else {  // ------------- d3: 3 WGs, ut 0..4 -------------
    const int ut = (wg - 61) * 2 + pair;
    const int utActive = (ut < 5) ? 1 : 0;
    float c[4][4] = {{0.f}};
    for (int t = 20; t < 400; ++t) {
      const int p = t & 1, q = p ^ 1;
      if (tid == 0)
        spin3(CNT(LD2, t), 8, t >= 21 ? CNT(LD3, t - 1) : nullptr, 3, nullptr, 0);
      __syncthreads();
      f32x4 acc[4][4];
      zacc44(acc);
      chunk_pass<256, 256>(lds, hb(HD2, p, 0, 256), hb(HD2, p, 1, 256), tid, lane, ut, utActive,
                           80, W + D3HI, W + D3LO, 352, 0, half, acc);
      chunk_pass<96, 128>(lds, hb(HLAST, q, 0, 96), hb(HLAST, q, 1, 96), tid, lane, ut, utActive,
                          80, W + D3HI, W + D3LO, 352, 256, half, acc);
      reduce_pair(lds, lane, pair, half, acc);
      if (!half && utActive)
        cell_update(lane, ut, 80, 96, d3b, acc, c, hb(HLAST, p, 0, 96), hb(HLAST, p, 1, 96),
                    dout + (size_t)(t - 20) * 80);
      vm_drain();
      __syncthreads();
      bump(LD3, t);
    }
  }
}

// ---------------- launch ----------------
extern "C" void kernel_launch(void* const* d_in, const int* in_sizes, int n_in, void* d_out,
                              int out_size, void* d_ws, size_t ws_size, hipStream_t stream) {
  if (ws_size < WS_NEED) return;

  const float* x = (const float*)d_in[0];
  const float* embW = (const float*)d_in[1];
  const float* embB = (const float*)d_in[2];
  const float* e1Wih = (const float*)d_in[3];
  const float* e1Whh = (const float*)d_in[4];
  const float* e1B = (const float*)d_in[5];
  const float* e2Wih = (const float*)d_in[6];
  const float* e2Whh = (const float*)d_in[7];
  const float* e2B = (const float*)d_in[8];
  const float* e3Wih = (const float*)d_in[9];
  const float* e3Whh = (const float*)d_in[10];
  const float* e3B = (const float*)d_in[11];
  const float* d1Wih = (const float*)d_in[12];
  const float* d1Whh = (const float*)d_in[13];
  const float* d1B = (const float*)d_in[14];
  const float* d2Wih = (const float*)d_in[15];
  const float* d2Whh = (const float*)d_in[16];
  const float* d2B = (const float*)d_in[17];
  const float* d3Wih = (const float*)d_in[18];
  const float* d3Whh = (const float*)d_in[19];
  const float* d3B = (const float*)d_in[20];
  const float* keyW = (const float*)d_in[21];
  const float* keyB = (const float*)d_in[22];
  const float* valW = (const float*)d_in[23];
  const float* valB = (const float*)d_in[24];

  unsigned char* ws = (unsigned char*)d_ws;
  unsigned short* W = (unsigned short*)ws;
  float* doutf = (float*)d_out;

  auto launch_w = [&](const float* wih, int din, const float* whh, int dh, int rows, int dinp,
                      int kp, size_t offhi, size_t offlo) {
    size_t tot = (size_t)rows * kp;
    int blocks = (int)((tot + 255) / 256);
    prep_w<<<blocks, 256, 0, stream>>>(wih, din, whh, dh, rows, dinp, kp, W + offhi, W + offlo);
  };
  launch_w(e1Wih, 80, e1Whh, 256, 1024, 96, 352, E1HI, E1LO);
  launch_w(e2Wih, 256, e2Whh, 256, 1024, 256, 512, E2HI, E2LO);
  launch_w(e3Wih, 256, e3Whh, 256, 1024, 256, 512, E3HI, E3LO);
  launch_w(d1Wih, 512, d1Whh, 256, 1024, 512, 768, D1HI, D1LO);
  launch_w(d2Wih, 256, d2Whh, 256, 1024, 256, 512, D2HI, D2LO);
  launch_w(d3Wih, 256, d3Whh, 80, 320, 256, 352, D3HI, D3LO);
  launch_w(keyW, 256, nullptr, 0, 256, 256, 256, KHI, KLO);
  launch_w(valW, 256, nullptr, 0, 256, 256, 256, VHI, VLO);
  launch_w(embW, 80, nullptr, 0, 256, 96, 96, EMHI, EMLO);
  prep_x<<<(int)((XPAD_ELEMS + 255) / 256), 256, 0, stream>>>(
      x, (unsigned short*)(ws + XPAD_HI_B), (unsigned short*)(ws + XPAD_LO_B));
  hipMemsetAsync(ws + STATE_B, 0, STATE_BYTES, stream);

  seq_main<<<dim3(NWG), dim3(WGS), 0, stream>>>(e1B, e2B, e3B, d1B, d2B, d3B, embB, keyB, valB,
                                                doutf, ws);
}

// Round 7
// 21436.066 us; speedup vs baseline: 8.2466x; 1.1124x over previous
//
#include <hip/hip_runtime.h>

typedef short bf16x8 __attribute__((ext_vector_type(8)));
typedef float f32x4 __attribute__((ext_vector_type(4)));

#define DEV static __device__ __forceinline__
#define SCOPE_AGENT __HIP_MEMORY_SCOPE_AGENT

// ---------------- numeric helpers ----------------
DEV unsigned short f2bf(float f) {
  unsigned u = __float_as_uint(f);
  unsigned r = u + 0x7fffu + ((u >> 16) & 1u);
  return (unsigned short)(r >> 16);
}
DEV float bf2f(unsigned short h) { return __uint_as_float(((unsigned)h) << 16); }
DEV void f2hilo(float f, unsigned short& hi, unsigned short& lo) {
  hi = f2bf(f);
  lo = f2bf(f - bf2f(hi));
}
DEV float sigm(float x) { return 1.f / (1.f + __expf(-x)); }
DEV float tanh_(float x) {
  x = fminf(15.f, fmaxf(-15.f, x));
  float e = __expf(2.f * x);
  return (e - 1.f) / (e + 1.f);
}

// ---------------- coherent (LLC) access helpers ----------------
DEV void st_sc_u16(unsigned short* p, unsigned short v) {
  __hip_atomic_store(p, v, __ATOMIC_RELAXED, SCOPE_AGENT);
}
DEV void st_sc_f32(float* p, float v) {
  __hip_atomic_store(p, v, __ATOMIC_RELAXED, SCOPE_AGENT);
}
DEV void st_sc_u64(unsigned long long* p, unsigned long long v) {
  __hip_atomic_store(p, v, __ATOMIC_RELAXED, SCOPE_AGENT);
}
DEV unsigned long long ld_sc_u64(const unsigned long long* p) {
  return __hip_atomic_load((unsigned long long*)p, __ATOMIC_RELAXED, SCOPE_AGENT);
}
DEV unsigned ld_sc_u32(const unsigned* p) {
  return __hip_atomic_load((unsigned*)p, __ATOMIC_RELAXED, SCOPE_AGENT);
}
DEV void vm_drain() { asm volatile("s_waitcnt vmcnt(0)" ::: "memory"); }

// ---------------- workspace layout ----------------
constexpr size_t WE1 = 1024 * 352, WE2 = 1024 * 512, WE3 = 1024 * 512,
                 WD1 = 1024 * 768, WD2 = 1024 * 512, WD3 = 320 * 352,
                 WKEY = 256 * 256, WVAL = 256 * 256, WEMB = 256 * 96;
constexpr size_t E1HI = 0, E1LO = E1HI + WE1, E2HI = E1LO + WE1, E2LO = E2HI + WE2,
                 E3HI = E2LO + WE2, E3LO = E3HI + WE3, D1HI = E3LO + WE3, D1LO = D1HI + WD1,
                 D2HI = D1LO + WD1, D2LO = D2HI + WD2, D3HI = D2LO + WD2, D3LO = D3HI + WD3,
                 KHI = D3LO + WD3, KLO = KHI + WKEY, VHI = KLO + WKEY, VLO = VHI + WVAL,
                 EMHI = VLO + WVAL, EMLO = EMHI + WEMB, WTOT = EMLO + WEMB;

constexpr size_t XPAD_ELEMS = (size_t)400 * 64 * 96;
constexpr size_t XPAD_HI_B = WTOT * 2;
constexpr size_t XPAD_LO_B = XPAD_HI_B + XPAD_ELEMS * 2;
constexpr size_t STATE_B = XPAD_LO_B + XPAD_ELEMS * 2;

// state (zeroed each launch): h buffers + flag arrays
constexpr size_t H256_SZB = (size_t)2 * 2 * 64 * 256 * 2;  // [parity][hi/lo][64][256] u16
constexpr size_t HE1 = 0, HE2 = H256_SZB, HE3 = 2 * H256_SZB, HD1 = 3 * H256_SZB,
                 HD2 = 4 * H256_SZB;
constexpr size_t HLAST = 5 * H256_SZB;  // [2][2][64][96] u16
constexpr size_t HLAST_SZB = (size_t)2 * 2 * 64 * 96 * 2;
constexpr size_t BARO = HLAST + HLAST_SZB;  // cnt[9][400] u32
constexpr size_t STATE_BYTES = BARO + 9 * 400 * 4 + 64;

// non-zeroed (fully rewritten before first read each launch)
constexpr size_t RINGK_B = STATE_B + STATE_BYTES;
constexpr size_t RING_SZ = (size_t)22 * 64 * 256 * 4;  // 22 slots: kv(t) only WARs attn(t-2)
constexpr size_t RINGV_B = RINGK_B + RING_SZ;
constexpr size_t CTXH_B = RINGV_B + RING_SZ;
constexpr size_t CTXL_B = CTXH_B + (size_t)64 * 256 * 2;
constexpr size_t D1BP_B = CTXL_B + (size_t)64 * 256 * 2;  // folded d1 bias f32[1024]
constexpr size_t WS_NEED = D1BP_B + 4096;

// layer flag ids; cnt[l][t] counts WGs of layer l done with step t
#define LE1 0
#define LE2 1
#define LE3 2
#define LKV 3
#define LAT 5
#define LD1 6
#define LD2 7
#define LD3 8
// WG map: e1 0-7 | e2 8-15 | e3 16-23 | kv 24-31 | at 32-47 | d1 48-55 | d2 56-63 | d3 64-66
// targets: e1/e2/e3/kv/d1/d2: 8, at: 16, d3: 3

constexpr int NWG = 67;
constexpr int WGS = 256;

// ---------------- prep kernels ----------------
__global__ void prep_w(const float* __restrict__ wih, int din, const float* __restrict__ whh,
                       int dh, int rows, int dinp, int kp, unsigned short* __restrict__ whi,
                       unsigned short* __restrict__ wlo) {
  size_t idx = (size_t)blockIdx.x * 256 + threadIdx.x;
  size_t tot = (size_t)rows * kp;
  if (idx >= tot) return;
  int j = (int)(idx / kp), k = (int)(idx % kp);
  float v = 0.f;
  if (k < dinp) {
    if (k < din) v = wih[(size_t)j * din + k];
  } else {
    int k2 = k - dinp;
    if (k2 < dh) v = whh[(size_t)j * dh + k2];
  }
  unsigned short hi, lo;
  f2hilo(v, hi, lo);
  whi[idx] = hi;
  wlo[idx] = lo;
}

// d1 folded weights: [1024][608] = [ W_comb(96: d1Wih[:, :256]@embW, cols>=80 zero) |
//                                    d1Wih[:,256:512] (ctx) | d1Whh (h) ]
__global__ void prep_d1_w(const float* __restrict__ wih, const float* __restrict__ whh,
                          const float* __restrict__ embW, unsigned short* __restrict__ whi,
                          unsigned short* __restrict__ wlo) {
  size_t idx = (size_t)blockIdx.x * 256 + threadIdx.x;
  constexpr size_t tot = (size_t)1024 * 608;
  if (idx >= tot) return;
  int j = (int)(idx / 608), f = (int)(idx % 608);
  float v = 0.f;
  if (f < 96) {
    if (f < 80) {
      const float* wr = wih + (size_t)j * 512;
#pragma unroll 4
      for (int m = 0; m < 256; m++) v += wr[m] * embW[(size_t)m * 80 + f];
    }
  } else if (f < 352) {
    v = wih[(size_t)j * 512 + 256 + (f - 96)];
  } else {
    v = whh[(size_t)j * 256 + (f - 352)];
  }
  unsigned short hi, lo;
  f2hilo(v, hi, lo);
  whi[idx] = hi;
  wlo[idx] = lo;
}

__global__ void prep_d1_bias(const float* __restrict__ wih, const float* __restrict__ embb,
                             const float* __restrict__ d1b, float* __restrict__ out) {
  int j = blockIdx.x * 256 + threadIdx.x;
  if (j >= 1024) return;
  float v = d1b[j];
  const float* wr = wih + (size_t)j * 512;
#pragma unroll 4
  for (int m = 0; m < 256; m++) v += wr[m] * embb[m];
  out[j] = v;
}

__global__ void prep_x(const float* __restrict__ x, unsigned short* __restrict__ xh,
                       unsigned short* __restrict__ xl) {
  size_t idx = (size_t)blockIdx.x * 256 + threadIdx.x;
  if (idx >= XPAD_ELEMS) return;
  int t = (int)(idx / 6144), rbf = (int)(idx % 6144), b = rbf / 96, f = rbf % 96;
  float v = (f < 80) ? x[(size_t)b * 32000 + (size_t)t * 80 + f] : 0.f;
  unsigned short hi, lo;
  f2hilo(v, hi, lo);
  xh[idx] = hi;
  xl[idx] = lo;
}

// ---------------- main kernel pieces ----------------
// LDS staging with 16B XOR swizzle: u16 col c -> c ^ ((row&7)<<3)

template <int COLS, int STRIDE>
DEV void copy_hl(unsigned short* lds, const unsigned short* hi, const unsigned short* lo,
                 int tid) {
  constexpr int CU64 = COLS / 4;
  constexpr int PER = 64 * CU64;
  constexpr int TOT = PER * 2;
  constexpr int loOff = 64 * STRIDE;
  for (int base = 0; base < TOT; base += WGS * 16) {
    unsigned long long v[16];
    int dst[16];
#pragma unroll
    for (int u = 0; u < 16; u++) {
      int i = base + u * WGS + tid;
      dst[u] = -1;
      if (i < TOT) {
        int pl = (i >= PER) ? 1 : 0;
        int j = pl ? (i - PER) : i;
        int row = j / CU64, cc = j - row * CU64;
        const unsigned long long* s = (const unsigned long long*)(pl ? lo : hi);
        v[u] = ld_sc_u64(s + j);
        dst[u] = (pl ? loOff : 0) + row * STRIDE + ((cc * 4) ^ ((row & 7) << 3));
      }
    }
#pragma unroll
    for (int u = 0; u < 16; u++)
      if (dst[u] >= 0) *(unsigned long long*)(lds + dst[u]) = v[u];
  }
}

DEV void mfma3(f32x4& acc, bf16x8 ah, bf16x8 al, bf16x8 bh, bf16x8 bl) {
  acc = __builtin_amdgcn_mfma_f32_16x16x32_bf16(ah, bh, acc, 0, 0, 0);
  acc = __builtin_amdgcn_mfma_f32_16x16x32_bf16(al, bh, acc, 0, 0, 0);
  acc = __builtin_amdgcn_mfma_f32_16x16x32_bf16(ah, bl, acc, 0, 0, 0);
}

DEV void zacc44(f32x4 (&a)[4][4]) {
#pragma unroll
  for (int g = 0; g < 4; g++)
#pragma unroll
    for (int m = 0; m < 4; m++) a[g][m] = f32x4{0.f, 0.f, 0.f, 0.f};
}

// MFMA over kb index range [kbLo,kbHi) of the staged chunk (K-split support)
template <int STRIDE>
DEV void mfma_range(const unsigned short* lds, int lane, int ut, int H,
                    const unsigned short* __restrict__ Whi,
                    const unsigned short* __restrict__ Wlo, int Kp, int kwOff, int kbLo,
                    int kbHi, f32x4 (&acc)[4][4]) {
  const int col = lane & 15, kg = lane >> 4;
  constexpr int loOff = 64 * STRIDE;
  for (int kb = kbLo; kb < kbHi; kb++) {
    const int ka = kb * 32 + kg * 8;
    bf16x8 ah[4], al[4];
#pragma unroll
    for (int m = 0; m < 4; m++) {
      int row = m * 16 + col;
      int off = row * STRIDE + (ka ^ ((row & 7) << 3));
      ah[m] = *(const bf16x8*)(lds + off);
      al[m] = *(const bf16x8*)(lds + loOff + off);
    }
#pragma unroll
    for (int g = 0; g < 4; g++) {
      size_t wr = (size_t)(g * H + ut * 16 + col) * Kp + kwOff + ka;
      bf16x8 bh = *(const bf16x8*)(Whi + wr);
      bf16x8 bl = *(const bf16x8*)(Wlo + wr);
#pragma unroll
      for (int m = 0; m < 4; m++) mfma3(acc[g][m], ah[m], al[m], bh, bl);
    }
  }
}

// one staged chunk: barrier, copy, barrier, half-K MFMA
template <int COLS, int STRIDE>
DEV void chunk_pass(unsigned short* lds, const unsigned short* hi, const unsigned short* lo,
                    int tid, int lane, int ut, int utActive, int H,
                    const unsigned short* __restrict__ Whi,
                    const unsigned short* __restrict__ Wlo, int Kp, int kwOff, int half,
                    f32x4 (&acc)[4][4]) {
  __syncthreads();  // previous LDS consumers done
  copy_hl<COLS, STRIDE>(lds, hi, lo, tid);
  __syncthreads();
  constexpr int NKB = COLS / 32;
  const int lo_kb = half ? (NKB + 1) / 2 : 0;
  const int hi_kb = half ? NKB : (NKB + 1) / 2;
  if (utActive) mfma_range<STRIDE>(lds, lane, ut, H, Whi, Wlo, Kp, kwOff, lo_kb, hi_kb, acc);
}

// combine the two K-halves: half1 writes partials to LDS, half0 adds
DEV void reduce_pair(unsigned short* lds, int lane, int pair, int half, f32x4 (&acc)[4][4]) {
  float* red = (float*)lds;
  const int base = (pair * 64 + lane) * 68;  // stride 68 f32 -> banks spread
  __syncthreads();
  if (half) {
#pragma unroll
    for (int g = 0; g < 4; g++)
#pragma unroll
      for (int m = 0; m < 4; m++)
#pragma unroll
        for (int r = 0; r < 4; r++) red[base + (g * 4 + m) * 4 + r] = acc[g][m][r];
  }
  __syncthreads();
  if (!half) {
#pragma unroll
    for (int g = 0; g < 4; g++)
#pragma unroll
      for (int m = 0; m < 4; m++)
#pragma unroll
        for (int r = 0; r < 4; r++) acc[g][m][r] += red[base + (g * 4 + m) * 4 + r];
  }
}

DEV void cell_update(int lane, int ut, int H, int Hpad, const float* __restrict__ bias,
                     f32x4 (&acc)[4][4], float (&c)[4][4], unsigned short* hwhi,
                     unsigned short* hwlo, float* outp) {
  const int col = lane & 15, kg = lane >> 4;
  const int u = ut * 16 + col;
  const float bi = bias[u], bff = bias[H + u], bg = bias[2 * H + u], bo = bias[3 * H + u];
#pragma unroll
  for (int m = 0; m < 4; m++)
#pragma unroll
    for (int r = 0; r < 4; r++) {
      int b = m * 16 + kg * 4 + r;
      float gi = acc[0][m][r] + bi, gf = acc[1][m][r] + bff;
      float gg = acc[2][m][r] + bg, go = acc[3][m][r] + bo;
      float cn = sigm(gf) * c[m][r] + sigm(gi) * tanh_(gg);
      float hh = sigm(go) * tanh_(cn);
      c[m][r] = cn;
      unsigned short hi, lo;
      f2hilo(hh, hi, lo);
      st_sc_u16(hwhi + b * Hpad + u, hi);
      st_sc_u16(hwlo + b * Hpad + u, lo);
      if (outp) outp[(size_t)b * 30400 + u] = hh;
    }
}

// linear (key/val): full-K per wave
template <int K, int STRIDE>
DEV void mfma_lin(const unsigned short* lds, int lane, int jt,
                  const unsigned short* __restrict__ Whi,
                  const unsigned short* __restrict__ Wlo, int Kp, f32x4 (&acc)[4]) {
  const int col = lane & 15, kg = lane >> 4;
  constexpr int loOff = 64 * STRIDE;
#pragma unroll
  for (int kb = 0; kb < K; kb += 32) {
    const int ka = kb + kg * 8;
    size_t wr = (size_t)(jt * 16 + col) * Kp + ka;
    bf16x8 bh = *(const bf16x8*)(Whi + wr);
    bf16x8 bl = *(const bf16x8*)(Wlo + wr);
#pragma unroll
    for (int m = 0; m < 4; m++) {
      int row = m * 16 + col;
      int off = row * STRIDE + (ka ^ ((row & 7) << 3));
      bf16x8 ah = *(const bf16x8*)(lds + off);
      bf16x8 al = *(const bf16x8*)(lds + loOff + off);
      mfma3(acc[m], ah, al, bh, bl);
    }
  }
}

// up to 3 flag waits; null ptr = skip
DEV void spin3(const unsigned* p0, unsigned t0, const unsigned* p1, unsigned t1,
               const unsigned* p2, unsigned t2) {
  for (;;) {
    unsigned a = p0 ? ld_sc_u32(p0) : 0xFFFFFFFFu;
    unsigned b = p1 ? ld_sc_u32(p1) : 0xFFFFFFFFu;
    unsigned c = p2 ? ld_sc_u32(p2) : 0xFFFFFFFFu;
    if (a >= t0 && b >= t1 && c >= t2) return;
    __builtin_amdgcn_s_sleep(1);
  }
}

// WAR/RAW audit:
//  HE1[p] by e1(t): readers e1(t-1){LE1 t-1}, e2(t-2){LE2 t-2}.
//  HE2[p] by e2(t): readers e2(t-1){LE2 t-1}, e3(t-2){LE3 t-2}.
//  HE3[p] by e3(t): readers e3(t-1){LE3 t-1}, kv(t-2){LKV t-2}.
//  HD1[p] by d1(t): readers d1(t-1){LD1 t-1}, d2(t-2){via LAT t chain}.
//  HD2[p] by d2(t): readers d2(t-1){LD2 t-1}, attn(t-1){via LD1 t: d1(t)<-at(t), at WGs
//    sequential so at(t) done => at(t-1) done}, d3(t-2){via LD1 t->...->LD3? covered: d2(t)
//    <-LD1(t)<-d1(t)<-LD3(t-1)=d3(t-1) done => d3(t-2) done, and d3(t-1) read HD2 parity q}.
//  HLAST[p] by d3(t): readers d3(t-1){LD3 t-1}, e1(t-1)+d1(t-1){via LD2 t chain:
//    d2(t)<-d1(t)<-at(t)<-kv(t-1)<-e3(t-1)<-e2(t-1)<-e1(t-1); d1(t)<-LD1(t-1)}.
//  ctx by attn(t): reader d1(t-1){LD1 t-1}.
//  ring slot t%22 by kv(t): reader attn(t-2){LAT t-2}.
__global__ void __launch_bounds__(WGS, 1)
seq_main(const float* e1b, const float* e2b, const float* e3b, const float* d2b,
         const float* d3b, const float* keyb, const float* valb, float* dout,
         unsigned char* ws) {
  __shared__ unsigned short lds_s[32768];  // 64 KB
  unsigned short* lds = lds_s;

  const int wg = blockIdx.x, tid = threadIdx.x;
  const int wv = tid >> 6, lane = tid & 63;
  const int pair = wv >> 1, half = wv & 1;

  unsigned short* W = (unsigned short*)ws;
  const unsigned short* xh = (const unsigned short*)(ws + XPAD_HI_B);
  const unsigned short* xl = (const unsigned short*)(ws + XPAD_LO_B);
  unsigned char* st = ws + STATE_B;
  float* ringk = (float*)(ws + RINGK_B);
  float* ringv = (float*)(ws + RINGV_B);
  unsigned short* ctxh = (unsigned short*)(ws + CTXH_B);
  unsigned short* ctxl = (unsigned short*)(ws + CTXL_B);
  const float* d1bp = (const float*)(ws + D1BP_B);
  unsigned* C = (unsigned*)(st + BARO);
  auto CNT = [&](int l, int tt) { return C + l * 400 + tt; };

  auto hb = [&](size_t off, int par, int hl, int Hpad) {
    return (unsigned short*)(st + off) + (size_t)(par * 2 + hl) * 64 * Hpad;
  };
  auto bump = [&](int l, int tt) {
    if (tid == 0) __hip_atomic_fetch_add(CNT(l, tt), 1u, __ATOMIC_RELAXED, SCOPE_AGENT);
  };

  if (wg < 8) {  // ------------- e1: 8 WGs, 2 ut/WG, K-split 2 -------------
    const int ut = wg * 2 + pair;
    float c[4][4] = {{0.f}};
    for (int t = 0; t < 400; ++t) {
      const int p = t & 1, q = p ^ 1;
      if (tid == 0)
        spin3(t >= 1 ? CNT(LE1, t - 1) : nullptr, 8, t >= 2 ? CNT(LE2, t - 2) : nullptr, 8,
              t >= 21 ? CNT(LD3, t - 1) : nullptr, 3);
      __syncthreads();
      f32x4 acc[4][4];
      zacc44(acc);
      if (t <= 20)
        chunk_pass<96, 128>(lds, xh + (size_t)t * 6144, xl + (size_t)t * 6144, tid, lane, ut, 1,
                            256, W + E1HI, W + E1LO, 352, 0, half, acc);
      else
        chunk_pass<96, 128>(lds, hb(HLAST, q, 0, 96), hb(HLAST, q, 1, 96), tid, lane, ut, 1,
                            256, W + E1HI, W + E1LO, 352, 0, half, acc);
      chunk_pass<256, 256>(lds, hb(HE1, q, 0, 256), hb(HE1, q, 1, 256), tid, lane, ut, 1, 256,
                           W + E1HI, W + E1LO, 352, 96, half, acc);
      reduce_pair(lds, lane, pair, half, acc);
      if (!half)
        cell_update(lane, ut, 256, 256, e1b, acc, c, hb(HE1, p, 0, 256), hb(HE1, p, 1, 256),
                    nullptr);
      vm_drain();
      __syncthreads();
      bump(LE1, t);
    }
  } else if (wg < 16) {  // ------------- e2 -------------
    const int ut = (wg - 8) * 2 + pair;
    float c[4][4] = {{0.f}};
    for (int t = 0; t < 400; ++t) {
      const int p = t & 1, q = p ^ 1;
      if (tid == 0)
        spin3(CNT(LE1, t), 8, t >= 1 ? CNT(LE2, t - 1) : nullptr, 8,
              t >= 2 ? CNT(LE3, t - 2) : nullptr, 8);
      __syncthreads();
      f32x4 acc[4][4];
      zacc44(acc);
      chunk_pass<256, 256>(lds, hb(HE1, p, 0, 256), hb(HE1, p, 1, 256), tid, lane, ut, 1, 256,
                           W + E2HI, W + E2LO, 512, 0, half, acc);
      chunk_pass<256, 256>(lds, hb(HE2, q, 0, 256), hb(HE2, q, 1, 256), tid, lane, ut, 1, 256,
                           W + E2HI, W + E2LO, 512, 256, half, acc);
      reduce_pair(lds, lane, pair, half, acc);
      if (!half)
        cell_update(lane, ut, 256, 256, e2b, acc, c, hb(HE2, p, 0, 256), hb(HE2, p, 1, 256),
                    nullptr);
      vm_drain();
      __syncthreads();
      bump(LE2, t);
    }
  } else if (wg < 24) {  // ------------- e3 -------------
    const int ut = (wg - 16) * 2 + pair;
    float c[4][4] = {{0.f}};
    for (int t = 0; t < 400; ++t) {
      const int p = t & 1, q = p ^ 1;
      if (tid == 0)
        spin3(CNT(LE2, t), 8, t >= 1 ? CNT(LE3, t - 1) : nullptr, 8,
              t >= 2 ? CNT(LKV, t - 2) : nullptr, 8);
      __syncthreads();
      f32x4 acc[4][4];
      zacc44(acc);
      chunk_pass<256, 256>(lds, hb(HE2, p, 0, 256), hb(HE2, p, 1, 256), tid, lane, ut, 1, 256,
                           W + E3HI, W + E3LO, 512, 0, half, acc);
      chunk_pass<256, 256>(lds, hb(HE3, q, 0, 256), hb(HE3, q, 1, 256), tid, lane, ut, 1, 256,
                           W + E3HI, W + E3LO, 512, 256, half, acc);
      reduce_pair(lds, lane, pair, half, acc);
      if (!half)
        cell_update(lane, ut, 256, 256, e3b, acc, c, hb(HE3, p, 0, 256), hb(HE3, p, 1, 256),
                    nullptr);
      vm_drain();
      __syncthreads();
      bump(LE3, t);
    }
  } else if (wg < 32) {  // ------------- kv: 8 WGs (24-27 key, 28-31 val), 1 jt/wave ----
    const bool isKey = wg < 28;
    const unsigned short* Whi = W + (isKey ? KHI : VHI);
    const unsigned short* Wlo = W + (isKey ? KLO : VLO);
    const float* bias = isKey ? keyb : valb;
    float* ring = isKey ? ringk : ringv;
    const int jt = (wg - (isKey ? 24 : 28)) * 4 + wv;
    const int col = lane & 15, kg = lane >> 4;
    for (int t = 0; t < 400; ++t) {
      const int p = t & 1;
      const int slot = t % 22;
      if (tid == 0)
        spin3(CNT(LE3, t), 8, t >= 22 ? CNT(LAT, t - 2) : nullptr, 16, nullptr, 0);
      __syncthreads();
      copy_hl<256, 256>(lds, hb(HE3, p, 0, 256), hb(HE3, p, 1, 256), tid);
      __syncthreads();
      float* outp = ring + (size_t)slot * 64 * 256;
      f32x4 acc[4];
#pragma unroll
      for (int m = 0; m < 4; m++) acc[m] = f32x4{0.f, 0.f, 0.f, 0.f};
      mfma_lin<256, 256>(lds, lane, jt, Whi, Wlo, 256, acc);
      int j = jt * 16 + col;
      float bj = bias[j];
#pragma unroll
      for (int m = 0; m < 4; m++)
#pragma unroll
        for (int r = 0; r < 4; r++) {
          int b = m * 16 + kg * 4 + r;
          st_sc_f32(outp + (size_t)b * 256 + j, acc[m][r] + bj);
        }
      vm_drain();
      __syncthreads();
      bump(LKV, t);
    }
  } else if (wg < 48) {  // ------------- attn: 16 WGs, 1 row/wave -------------
    const int b = (wg - 32) * 4 + wv;
    for (int t = 20; t < 400; ++t) {
      const int q = (t & 1) ^ 1;
      if (t == 20) {
        if (tid == 0) spin3(CNT(LKV, 20), 8, nullptr, 0, nullptr, 0);
        __syncthreads();
        // ctx := v20 (ring slot 20)
        const unsigned long long* vp =
            (const unsigned long long*)(ringv + ((size_t)20 * 64 + b) * 256 + lane * 4);
        unsigned long long v0 = ld_sc_u64(vp), v1 = ld_sc_u64(vp + 1);
        float f[4] = {__uint_as_float((unsigned)v0), __uint_as_float((unsigned)(v0 >> 32)),
                      __uint_as_float((unsigned)v1), __uint_as_float((unsigned)(v1 >> 32))};
        unsigned short hi[4], lo[4];
#pragma unroll
        for (int j = 0; j < 4; j++) f2hilo(f[j], hi[j], lo[j]);
        unsigned long long ph = (unsigned long long)hi[0] | ((unsigned long long)hi[1] << 16) |
                                ((unsigned long long)hi[2] << 32) |
                                ((unsigned long long)hi[3] << 48);
        unsigned long long pl = (unsigned long long)lo[0] | ((unsigned long long)lo[1] << 16) |
                                ((unsigned long long)lo[2] << 32) |
                                ((unsigned long long)lo[3] << 48);
        st_sc_u64((unsigned long long*)(ctxh + b * 256 + lane * 4), ph);
        st_sc_u64((unsigned long long*)(ctxl + b * 256 + lane * 4), pl);
      } else {
        if (tid == 0)
          spin3(CNT(LKV, t - 1), 8, CNT(LD2, t - 1), 8, CNT(LD1, t - 1), 8);
        __syncthreads();
        const unsigned short* qh = hb(HD2, q, 0, 256);
        const unsigned short* ql = hb(HD2, q, 1, 256);
        unsigned long long hq = ld_sc_u64((const unsigned long long*)(qh + b * 256 + lane * 4));
        unsigned long long lq = ld_sc_u64((const unsigned long long*)(ql + b * 256 + lane * 4));
        float qv[4];
#pragma unroll
        for (int j = 0; j < 4; j++)
          qv[j] = bf2f((unsigned short)(hq >> (16 * j))) + bf2f((unsigned short)(lq >> (16 * j)));
        float s[20];
#pragma unroll
        for (int i = 0; i < 20; i++) {
          int slot = (t - 20 + i) % 22;
          const unsigned long long* kp =
              (const unsigned long long*)(ringk + ((size_t)slot * 64 + b) * 256 + lane * 4);
          unsigned long long k0 = ld_sc_u64(kp), k1 = ld_sc_u64(kp + 1);
          s[i] = __uint_as_float((unsigned)k0) * qv[0] +
                 __uint_as_float((unsigned)(k0 >> 32)) * qv[1] +
                 __uint_as_float((unsigned)k1) * qv[2] +
                 __uint_as_float((unsigned)(k1 >> 32)) * qv[3];
        }
#pragma unroll
        for (int off = 32; off >= 1; off >>= 1)
#pragma unroll
          for (int i = 0; i < 20; i++) s[i] += __shfl_xor(s[i], off, 64);
        float mx = s[0];
#pragma unroll
        for (int i = 1; i < 20; i++) mx = fmaxf(mx, s[i]);
        float den = 0.f;
#pragma unroll
        for (int i = 0; i < 20; i++) {
          s[i] = __expf(s[i] - mx);
          den += s[i];
        }
        float inv = 1.f / den;
        float a0 = 0.f, a1 = 0.f, a2 = 0.f, a3 = 0.f;
#pragma unroll
        for (int i = 0; i < 20; i++) {
          int slot = (t - 20 + i) % 22;
          const unsigned long long* vp =
              (const unsigned long long*)(ringv + ((size_t)slot * 64 + b) * 256 + lane * 4);
          unsigned long long v0 = ld_sc_u64(vp), v1 = ld_sc_u64(vp + 1);
          a0 += s[i] * __uint_as_float((unsigned)v0);
          a1 += s[i] * __uint_as_float((unsigned)(v0 >> 32));
          a2 += s[i] * __uint_as_float((unsigned)v1);
          a3 += s[i] * __uint_as_float((unsigned)(v1 >> 32));
        }
        float f[4] = {a0 * inv, a1 * inv, a2 * inv, a3 * inv};
        unsigned short hi[4], lo[4];
#pragma unroll
        for (int j = 0; j < 4; j++) f2hilo(f[j], hi[j], lo[j]);
        unsigned long long ph = (unsigned long long)hi[0] | ((unsigned long long)hi[1] << 16) |
                                ((unsigned long long)hi[2] << 32) |
                                ((unsigned long long)hi[3] << 48);
        unsigned long long pl = (unsigned long long)lo[0] | ((unsigned long long)lo[1] << 16) |
                                ((unsigned long long)lo[2] << 32) |
                                ((unsigned long long)lo[3] << 48);
        st_sc_u64((unsigned long long*)(ctxh + b * 256 + lane * 4), ph);
        st_sc_u64((unsigned long long*)(ctxl + b * 256 + lane * 4), pl);
      }
      vm_drain();
      __syncthreads();
      bump(LAT, t);
    }
  } else if (wg < 56) {  // ------------- d1 (emb folded): K = 96|256|256, Kp=608 -------
    const int ut = (wg - 48) * 2 + pair;
    float c[4][4] = {{0.f}};
    for (int t = 20; t < 400; ++t) {
      const int p = t & 1, q = p ^ 1;
      if (tid == 0)
        spin3(t >= 21 ? CNT(LD3, t - 1) : nullptr, 3, CNT(LAT, t), 16,
              t >= 21 ? CNT(LD1, t - 1) : nullptr, 8);
      __syncthreads();
      f32x4 acc[4][4];
      zacc44(acc);
      if (t == 20)
        chunk_pass<96, 128>(lds, xh + (size_t)19 * 6144, xl + (size_t)19 * 6144, tid, lane, ut,
                            1, 256, W + D1HI, W + D1LO, 608, 0, half, acc);
      else
        chunk_pass<96, 128>(lds, hb(HLAST, q, 0, 96), hb(HLAST, q, 1, 96), tid, lane, ut, 1,
                            256, W + D1HI, W + D1LO, 608, 0, half, acc);
      chunk_pass<256, 256>(lds, ctxh, ctxl, tid, lane, ut, 1, 256, W + D1HI, W + D1LO, 608, 96,
                           half, acc);
      chunk_pass<256, 256>(lds, hb(HD1, q, 0, 256), hb(HD1, q, 1, 256), tid, lane, ut, 1, 256,
                           W + D1HI, W + D1LO, 608, 352, half, acc);
      reduce_pair(lds, lane, pair, half, acc);
      if (!half)
        cell_update(lane, ut, 256, 256, d1bp, acc, c, hb(HD1, p, 0, 256), hb(HD1, p, 1, 256),
                    nullptr);
      vm_drain();
      __syncthreads();
      bump(LD1, t);
    }
  } else if (wg < 64) {  // ------------- d2 -------------
    const int ut = (wg - 56) * 2 + pair;
    float c[4][4] = {{0.f}};
    for (int t = 20; t < 400; ++t) {
      const int p = t & 1, q = p ^ 1;
      if (tid == 0)
        spin3(CNT(LD1, t), 8, t >= 21 ? CNT(LD2, t - 1) : nullptr, 8, nullptr, 0);
      __syncthreads();
      f32x4 acc[4][4];
      zacc44(acc);
      chunk_pass<256, 256>(lds, hb(HD1, p, 0, 256), hb(HD1, p, 1, 256), tid, lane, ut, 1, 256,
                           W + D2HI, W + D2LO, 512, 0, half, acc);
      chunk_pass<256, 256>(lds, hb(HD2, q, 0, 256), hb(HD2, q, 1, 256), tid, lane, ut, 1, 256,
                           W + D2HI, W + D2LO, 512, 256, half, acc);
      reduce_pair(lds, lane, pair, half, acc);
      if (!half)
        cell_update(lane, ut, 256, 256, d2b, acc, c, hb(HD2, p, 0, 256), hb(HD2, p, 1, 256),
                    nullptr);
      vm_drain();
      __syncthreads();
      bump(LD2, t);
    }
  } else {  // ------------- d3: 3 WGs, ut 0..4 -------------
    const int ut = (wg - 64) * 2 + pair;
    const int utActive = (ut < 5) ? 1 : 0;
    float c[4][4] = {{0.f}};
    for (int t = 20; t < 400; ++t) {
      const int p = t & 1, q = p ^ 1;
      if (tid == 0)
        spin3(CNT(LD2, t), 8, t >= 21 ? CNT(LD3, t - 1) : nullptr, 3, nullptr, 0);
      __syncthreads();
      f32x4 acc[4][4];
      zacc44(acc);
      chunk_pass<256, 256>(lds, hb(HD2, p, 0, 256), hb(HD2, p, 1, 256), tid, lane, ut, utActive,
                           80, W + D3HI, W + D3LO, 352, 0, half, acc);
      chunk_pass<96, 128>(lds, hb(HLAST, q, 0, 96), hb(HLAST, q, 1, 96), tid, lane, ut, utActive,
                          80, W + D3HI, W + D3LO, 352, 256, half, acc);
      reduce_pair(lds, lane, pair, half, acc);
      if (!half && utActive)
        cell_update(lane, ut, 80, 96, d3b, acc, c, hb(HLAST, p, 0, 96), hb(HLAST, p, 1, 96),
                    dout + (size_t)(t - 20) * 80);
      vm_drain();
      __syncthreads();
      bump(LD3, t);
    }
  }
}

// ---------------- launch ----------------
extern "C" void kernel_launch(void* const* d_in, const int* in_sizes, int n_in, void* d_out,
                              int out_size, void* d_ws, size_t ws_size, hipStream_t stream) {
  if (ws_size < WS_NEED) return;

  const float* x = (const float*)d_in[0];
  const float* embW = (const float*)d_in[1];
  const float* embB = (const float*)d_in[2];
  const float* e1Wih = (const float*)d_in[3];
  const float* e1Whh = (const float*)d_in[4];
  const float* e1B = (const float*)d_in[5];
  const float* e2Wih = (const float*)d_in[6];
  const float* e2Whh = (const float*)d_in[7];
  const float* e2B = (const float*)d_in[8];
  const float* e3Wih = (const float*)d_in[9];
  const float* e3Whh = (const float*)d_in[10];
  const float* e3B = (const float*)d_in[11];
  const float* d1Wih = (const float*)d_in[12];
  const float* d1Whh = (const float*)d_in[13];
  const float* d1B = (const float*)d_in[14];
  const float* d2Wih = (const float*)d_in[15];
  const float* d2Whh = (const float*)d_in[16];
  const float* d2B = (const float*)d_in[17];
  const float* d3Wih = (const float*)d_in[18];
  const float* d3Whh = (const float*)d_in[19];
  const float* d3B = (const float*)d_in[20];
  const float* keyW = (const float*)d_in[21];
  const float* keyB = (const float*)d_in[22];
  const float* valW = (const float*)d_in[23];
  const float* valB = (const float*)d_in[24];

  unsigned char* ws = (unsigned char*)d_ws;
  unsigned short* W = (unsigned short*)ws;
  float* doutf = (float*)d_out;

  auto launch_w = [&](const float* wih, int din, const float* whh, int dh, int rows, int dinp,
                      int kp, size_t offhi, size_t offlo) {
    size_t tot = (size_t)rows * kp;
    int blocks = (int)((tot + 255) / 256);
    prep_w<<<blocks, 256, 0, stream>>>(wih, din, whh, dh, rows, dinp, kp, W + offhi, W + offlo);
  };
  launch_w(e1Wih, 80, e1Whh, 256, 1024, 96, 352, E1HI, E1LO);
  launch_w(e2Wih, 256, e2Whh, 256, 1024, 256, 512, E2HI, E2LO);
  launch_w(e3Wih, 256, e3Whh, 256, 1024, 256, 512, E3HI, E3LO);
  launch_w(d2Wih, 256, d2Whh, 256, 1024, 256, 512, D2HI, D2LO);
  launch_w(d3Wih, 256, d3Whh, 80, 320, 256, 352, D3HI, D3LO);
  launch_w(keyW, 256, nullptr, 0, 256, 256, 256, KHI, KLO);
  launch_w(valW, 256, nullptr, 0, 256, 256, 256, VHI, VLO);
  // d1 folded weights + bias
  {
    size_t tot = (size_t)1024 * 608;
    prep_d1_w<<<(int)((tot + 255) / 256), 256, 0, stream>>>(d1Wih, d1Whh, embW, W + D1HI,
                                                            W + D1LO);
    prep_d1_bias<<<4, 256, 0, stream>>>(d1Wih, embB, d1B, (float*)(ws + D1BP_B));
  }
  prep_x<<<(int)((XPAD_ELEMS + 255) / 256), 256, 0, stream>>>(
      x, (unsigned short*)(ws + XPAD_HI_B), (unsigned short*)(ws + XPAD_LO_B));
  hipMemsetAsync(ws + STATE_B, 0, STATE_BYTES, stream);

  seq_main<<<dim3(NWG), dim3(WGS), 0, stream>>>(e1B, e2B, e3B, d2B, d3B, keyB, valB, doutf, ws);
}

// Round 8
// 14991.397 us; speedup vs baseline: 11.7918x; 1.4299x over previous
//
#include <hip/hip_runtime.h>

typedef short bf16x8 __attribute__((ext_vector_type(8)));
typedef float f32x4 __attribute__((ext_vector_type(4)));

#define DEV static __device__ __forceinline__
#define SCOPE_AGENT __HIP_MEMORY_SCOPE_AGENT

// ---------------- numeric helpers ----------------
DEV unsigned short f2bf(float f) {
  unsigned u = __float_as_uint(f);
  unsigned r = u + 0x7fffu + ((u >> 16) & 1u);
  return (unsigned short)(r >> 16);
}
DEV float bf2f(unsigned short h) { return __uint_as_float(((unsigned)h) << 16); }
DEV void f2hilo(float f, unsigned short& hi, unsigned short& lo) {
  hi = f2bf(f);
  lo = f2bf(f - bf2f(hi));
}
DEV float sigm(float x) { return 1.f / (1.f + __expf(-x)); }
DEV float tanh_(float x) {
  x = fminf(15.f, fmaxf(-15.f, x));
  float e = __expf(2.f * x);
  return (e - 1.f) / (e + 1.f);
}

// ---------------- coherent (LLC) access helpers ----------------
DEV void st_sc_u16(unsigned short* p, unsigned short v) {
  __hip_atomic_store(p, v, __ATOMIC_RELAXED, SCOPE_AGENT);
}
DEV void st_sc_f32(float* p, float v) {
  __hip_atomic_store(p, v, __ATOMIC_RELAXED, SCOPE_AGENT);
}
DEV void st_sc_u64(unsigned long long* p, unsigned long long v) {
  __hip_atomic_store(p, v, __ATOMIC_RELAXED, SCOPE_AGENT);
}
DEV unsigned long long ld_sc_u64(const unsigned long long* p) {
  return __hip_atomic_load((unsigned long long*)p, __ATOMIC_RELAXED, SCOPE_AGENT);
}
DEV unsigned ld_sc_u32(const unsigned* p) {
  return __hip_atomic_load((unsigned*)p, __ATOMIC_RELAXED, SCOPE_AGENT);
}
DEV void vm_drain() { asm volatile("s_waitcnt vmcnt(0)" ::: "memory"); }

// ---------------- workspace layout ----------------
constexpr size_t WE1 = 1024 * 352, WE2 = 1024 * 512, WE3 = 1024 * 512,
                 WD1 = 1024 * 768, WD2 = 1024 * 512, WD3 = 320 * 352,
                 WKEY = 256 * 256, WVAL = 256 * 256, WEMB = 256 * 96;
constexpr size_t E1HI = 0, E1LO = E1HI + WE1, E2HI = E1LO + WE1, E2LO = E2HI + WE2,
                 E3HI = E2LO + WE2, E3LO = E3HI + WE3, D1HI = E3LO + WE3, D1LO = D1HI + WD1,
                 D2HI = D1LO + WD1, D2LO = D2HI + WD2, D3HI = D2LO + WD2, D3LO = D3HI + WD3,
                 KHI = D3LO + WD3, KLO = KHI + WKEY, VHI = KLO + WKEY, VLO = VHI + WVAL,
                 EMHI = VLO + WVAL, EMLO = EMHI + WEMB, WTOT = EMLO + WEMB;

constexpr size_t XPAD_ELEMS = (size_t)400 * 64 * 96;
constexpr size_t XPAD_HI_B = WTOT * 2;
constexpr size_t XPAD_LO_B = XPAD_HI_B + XPAD_ELEMS * 2;
constexpr size_t STATE_B = XPAD_LO_B + XPAD_ELEMS * 2;

// state (zeroed each launch): h buffers + flag arrays
constexpr size_t H256_SZB = (size_t)2 * 2 * 64 * 256 * 2;  // [parity][hi/lo][64][256] u16
constexpr size_t HE1 = 0, HE2 = H256_SZB, HE3 = 2 * H256_SZB, HD1 = 3 * H256_SZB,
                 HD2 = 4 * H256_SZB;
constexpr size_t HLAST = 5 * H256_SZB;  // [2][2][64][96] u16
constexpr size_t HLAST_SZB = (size_t)2 * 2 * 64 * 96 * 2;
constexpr size_t BARO = HLAST + HLAST_SZB;  // cnt[9][400] u32
constexpr size_t STATE_BYTES = BARO + 9 * 400 * 4 + 64;

// non-zeroed (fully rewritten before first read each launch)
constexpr size_t RINGK_B = STATE_B + STATE_BYTES;
constexpr size_t RING_SZ = (size_t)22 * 64 * 256 * 4;  // 22 slots: kv(t) only WARs attn(t-2)
constexpr size_t RINGV_B = RINGK_B + RING_SZ;
constexpr size_t CTXH_B = RINGV_B + RING_SZ;
constexpr size_t CTXL_B = CTXH_B + (size_t)64 * 256 * 2;
constexpr size_t D1BP_B = CTXL_B + (size_t)64 * 256 * 2;  // folded d1 bias f32[1024]
constexpr size_t WS_NEED = D1BP_B + 4096;

// layer flag ids; cnt[l][t] counts WGs of layer l done with step t
#define LE1 0
#define LE2 1
#define LE3 2
#define LKV 3
#define LAT 5
#define LD1 6
#define LD2 7
#define LD3 8
// WG map: e1 0-7 | e2 8-15 | e3 16-23 | kv 24-31 | at 32-47 | d1 48-55 | d2 56-63 | d3 64-66
// targets: e1/e2/e3/kv/d1/d2: 8, at: 16, d3: 3

constexpr int NWG = 67;
constexpr int WGS = 256;

// ---------------- prep kernels ----------------
__global__ void prep_w(const float* __restrict__ wih, int din, const float* __restrict__ whh,
                       int dh, int rows, int dinp, int kp, unsigned short* __restrict__ whi,
                       unsigned short* __restrict__ wlo) {
  size_t idx = (size_t)blockIdx.x * 256 + threadIdx.x;
  size_t tot = (size_t)rows * kp;
  if (idx >= tot) return;
  int j = (int)(idx / kp), k = (int)(idx % kp);
  float v = 0.f;
  if (k < dinp) {
    if (k < din) v = wih[(size_t)j * din + k];
  } else {
    int k2 = k - dinp;
    if (k2 < dh) v = whh[(size_t)j * dh + k2];
  }
  unsigned short hi, lo;
  f2hilo(v, hi, lo);
  whi[idx] = hi;
  wlo[idx] = lo;
}

// d1 folded weights: [1024][608] = [ W_comb(96: d1Wih[:, :256]@embW, cols>=80 zero) |
//                                    d1Wih[:,256:512] (ctx) | d1Whh (h) ]
__global__ void prep_d1_w(const float* __restrict__ wih, const float* __restrict__ whh,
                          const float* __restrict__ embW, unsigned short* __restrict__ whi,
                          unsigned short* __restrict__ wlo) {
  size_t idx = (size_t)blockIdx.x * 256 + threadIdx.x;
  constexpr size_t tot = (size_t)1024 * 608;
  if (idx >= tot) return;
  int j = (int)(idx / 608), f = (int)(idx % 608);
  float v = 0.f;
  if (f < 96) {
    if (f < 80) {
      const float* wr = wih + (size_t)j * 512;
#pragma unroll 4
      for (int m = 0; m < 256; m++) v += wr[m] * embW[(size_t)m * 80 + f];
    }
  } else if (f < 352) {
    v = wih[(size_t)j * 512 + 256 + (f - 96)];
  } else {
    v = whh[(size_t)j * 256 + (f - 352)];
  }
  unsigned short hi, lo;
  f2hilo(v, hi, lo);
  whi[idx] = hi;
  wlo[idx] = lo;
}

__global__ void prep_d1_bias(const float* __restrict__ wih, const float* __restrict__ embb,
                             const float* __restrict__ d1b, float* __restrict__ out) {
  int j = blockIdx.x * 256 + threadIdx.x;
  if (j >= 1024) return;
  float v = d1b[j];
  const float* wr = wih + (size_t)j * 512;
#pragma unroll 4
  for (int m = 0; m < 256; m++) v += wr[m] * embb[m];
  out[j] = v;
}

__global__ void prep_x(const float* __restrict__ x, unsigned short* __restrict__ xh,
                       unsigned short* __restrict__ xl) {
  size_t idx = (size_t)blockIdx.x * 256 + threadIdx.x;
  if (idx >= XPAD_ELEMS) return;
  int t = (int)(idx / 6144), rbf = (int)(idx % 6144), b = rbf / 96, f = rbf % 96;
  float v = (f < 80) ? x[(size_t)b * 32000 + (size_t)t * 80 + f] : 0.f;
  unsigned short hi, lo;
  f2hilo(v, hi, lo);
  xh[idx] = hi;
  xl[idx] = lo;
}

// ---------------- main kernel pieces ----------------
// LDS staging with 16B XOR swizzle: u16 col c -> c ^ ((row&7)<<3)

template <int COLS, int STRIDE>
DEV void copy_hl(unsigned short* lds, const unsigned short* hi, const unsigned short* lo,
                 int tid) {
  constexpr int CU64 = COLS / 4;
  constexpr int PER = 64 * CU64;
  constexpr int TOT = PER * 2;
  constexpr int loOff = 64 * STRIDE;
  for (int base = 0; base < TOT; base += WGS * 16) {
    unsigned long long v[16];
    int dst[16];
#pragma unroll
    for (int u = 0; u < 16; u++) {
      int i = base + u * WGS + tid;
      dst[u] = -1;
      if (i < TOT) {
        int pl = (i >= PER) ? 1 : 0;
        int j = pl ? (i - PER) : i;
        int row = j / CU64, cc = j - row * CU64;
        const unsigned long long* s = (const unsigned long long*)(pl ? lo : hi);
        v[u] = ld_sc_u64(s + j);
        dst[u] = (pl ? loOff : 0) + row * STRIDE + ((cc * 4) ^ ((row & 7) << 3));
      }
    }
#pragma unroll
    for (int u = 0; u < 16; u++)
      if (dst[u] >= 0) *(unsigned long long*)(lds + dst[u]) = v[u];
  }
}

DEV void mfma3(f32x4& acc, bf16x8 ah, bf16x8 al, bf16x8 bh, bf16x8 bl) {
  acc = __builtin_amdgcn_mfma_f32_16x16x32_bf16(ah, bh, acc, 0, 0, 0);
  acc = __builtin_amdgcn_mfma_f32_16x16x32_bf16(al, bh, acc, 0, 0, 0);
  acc = __builtin_amdgcn_mfma_f32_16x16x32_bf16(ah, bl, acc, 0, 0, 0);
}

DEV void zacc44(f32x4 (&a)[4][4]) {
#pragma unroll
  for (int g = 0; g < 4; g++)
#pragma unroll
    for (int m = 0; m < 4; m++) a[g][m] = f32x4{0.f, 0.f, 0.f, 0.f};
}

// MFMA over kb index range [kbLo,kbHi) of the staged chunk (K-split support)
template <int STRIDE>
DEV void mfma_range(const unsigned short* lds, int lane, int ut, int H,
                    const unsigned short* __restrict__ Whi,
                    const unsigned short* __restrict__ Wlo, int Kp, int kwOff, int kbLo,
                    int kbHi, f32x4 (&acc)[4][4]) {
  const int col = lane & 15, kg = lane >> 4;
  constexpr int loOff = 64 * STRIDE;
  for (int kb = kbLo; kb < kbHi; kb++) {
    const int ka = kb * 32 + kg * 8;
    bf16x8 ah[4], al[4];
#pragma unroll
    for (int m = 0; m < 4; m++) {
      int row = m * 16 + col;
      int off = row * STRIDE + (ka ^ ((row & 7) << 3));
      ah[m] = *(const bf16x8*)(lds + off);
      al[m] = *(const bf16x8*)(lds + loOff + off);
    }
#pragma unroll
    for (int g = 0; g < 4; g++) {
      size_t wr = (size_t)(g * H + ut * 16 + col) * Kp + kwOff + ka;
      bf16x8 bh = *(const bf16x8*)(Whi + wr);
      bf16x8 bl = *(const bf16x8*)(Wlo + wr);
#pragma unroll
      for (int m = 0; m < 4; m++) mfma3(acc[g][m], ah[m], al[m], bh, bl);
    }
  }
}

// one staged chunk: barrier, copy, barrier, half-K MFMA
template <int COLS, int STRIDE>
DEV void chunk_pass(unsigned short* lds, const unsigned short* hi, const unsigned short* lo,
                    int tid, int lane, int ut, int utActive, int H,
                    const unsigned short* __restrict__ Whi,
                    const unsigned short* __restrict__ Wlo, int Kp, int kwOff, int half,
                    f32x4 (&acc)[4][4]) {
  __syncthreads();  // releases spin + previous LDS consumers done
  copy_hl<COLS, STRIDE>(lds, hi, lo, tid);
  __syncthreads();
  constexpr int NKB = COLS / 32;
  const int lo_kb = half ? (NKB + 1) / 2 : 0;
  const int hi_kb = half ? NKB : (NKB + 1) / 2;
  if (utActive) mfma_range<STRIDE>(lds, lane, ut, H, Whi, Wlo, Kp, kwOff, lo_kb, hi_kb, acc);
}

// combine the two K-halves: half1 writes partials to LDS, half0 adds
DEV void reduce_pair(unsigned short* lds, int lane, int pair, int half, f32x4 (&acc)[4][4]) {
  float* red = (float*)lds;
  const int base = (pair * 64 + lane) * 68;  // stride 68 f32 -> banks spread
  __syncthreads();
  if (half) {
#pragma unroll
    for (int g = 0; g < 4; g++)
#pragma unroll
      for (int m = 0; m < 4; m++)
#pragma unroll
        for (int r = 0; r < 4; r++) red[base + (g * 4 + m) * 4 + r] = acc[g][m][r];
  }
  __syncthreads();
  if (!half) {
#pragma unroll
    for (int g = 0; g < 4; g++)
#pragma unroll
      for (int m = 0; m < 4; m++)
#pragma unroll
        for (int r = 0; r < 4; r++) acc[g][m][r] += red[base + (g * 4 + m) * 4 + r];
  }
}

DEV void cell_update(int lane, int ut, int H, int Hpad, const float* __restrict__ bias,
                     f32x4 (&acc)[4][4], float (&c)[4][4], unsigned short* hwhi,
                     unsigned short* hwlo, float* outp) {
  const int col = lane & 15, kg = lane >> 4;
  const int u = ut * 16 + col;
  const float bi = bias[u], bff = bias[H + u], bg = bias[2 * H + u], bo = bias[3 * H + u];
#pragma unroll
  for (int m = 0; m < 4; m++)
#pragma unroll
    for (int r = 0; r < 4; r++) {
      int b = m * 16 + kg * 4 + r;
      float gi = acc[0][m][r] + bi, gf = acc[1][m][r] + bff;
      float gg = acc[2][m][r] + bg, go = acc[3][m][r] + bo;
      float cn = sigm(gf) * c[m][r] + sigm(gi) * tanh_(gg);
      float hh = sigm(go) * tanh_(cn);
      c[m][r] = cn;
      unsigned short hi, lo;
      f2hilo(hh, hi, lo);
      st_sc_u16(hwhi + b * Hpad + u, hi);
      st_sc_u16(hwlo + b * Hpad + u, lo);
      if (outp) outp[(size_t)b * 30400 + u] = hh;
    }
}

// linear (key/val): full-K per wave
template <int K, int STRIDE>
DEV void mfma_lin(const unsigned short* lds, int lane, int jt,
                  const unsigned short* __restrict__ Whi,
                  const unsigned short* __restrict__ Wlo, int Kp, f32x4 (&acc)[4]) {
  const int col = lane & 15, kg = lane >> 4;
  constexpr int loOff = 64 * STRIDE;
#pragma unroll
  for (int kb = 0; kb < K; kb += 32) {
    const int ka = kb + kg * 8;
    size_t wr = (size_t)(jt * 16 + col) * Kp + ka;
    bf16x8 bh = *(const bf16x8*)(Whi + wr);
    bf16x8 bl = *(const bf16x8*)(Wlo + wr);
#pragma unroll
    for (int m = 0; m < 4; m++) {
      int row = m * 16 + col;
      int off = row * STRIDE + (ka ^ ((row & 7) << 3));
      bf16x8 ah = *(const bf16x8*)(lds + off);
      bf16x8 al = *(const bf16x8*)(lds + loOff + off);
      mfma3(acc[m], ah, al, bh, bl);
    }
  }
}

// up to 3 flag waits; null ptr = skip
DEV void spin3(const unsigned* p0, unsigned t0, const unsigned* p1, unsigned t1,
               const unsigned* p2, unsigned t2) {
  for (;;) {
    unsigned a = p0 ? ld_sc_u32(p0) : 0xFFFFFFFFu;
    unsigned b = p1 ? ld_sc_u32(p1) : 0xFFFFFFFFu;
    unsigned c = p2 ? ld_sc_u32(p2) : 0xFFFFFFFFu;
    if (a >= t0 && b >= t1 && c >= t2) return;
    __builtin_amdgcn_s_sleep(1);
  }
}

// WAR/RAW audit (chunk-reordered version; own/old chunk first, fresh dep last):
//  e1(t): [A: LE1 t-1] own HE1[q]; [B: LD3 t-1 (RAW hlast), LE2 t-2 (WAR HE1[p])] x/hlast.
//  e2(t): [A: LE2 t-1] own HE2[q]; [B: LE1 t (RAW), LE3 t-2 (WAR HE2[p])] HE1[p].
//  e3(t): [A: LE3 t-1] own HE3[q]; [B: LE2 t (RAW), LKV t-2 (WAR HE3[p])] HE2[p].
//  kv(t): [LE3 t (RAW), LAT t-2 (WAR ring slot t%22)] HE3[p].
//  at(t): [LKV t-1 (RAW ring), LD2 t-1 (RAW q), LD1 t-1 (WAR ctx)].
//  d1(t): [A: LD1 t-1 (RAW own + WAR HD1[p]; d2(t-2) covered via LAT t <= LD2 t-1)]
//         own HD1[q]; [B: LD3 t-1] hlast/x19; [C: LAT t] ctx.
//  d2(t): [A: LD2 t-1] own HD2[q]; [B: LD1 t (RAW; also covers WAR HD2[p]: at(t-1) &
//         d3(t-2) via LD1 t <= LAT t <= LD2 t-1 <= LD1 t-1 <= d1(t-1) <= LD3 t-2)] HD1[p].
//  d3(t): [A: LD3 t-1] own HLAST[q]; [B: LD2 t (RAW; WAR HLAST[p]: e1(t-1)/d1(t-1) covered
//         via LD2 t <= LD1 t <= LAT t <= LKV t-1 <= e3,e2,e1(t-1), and LD1 t => d1(t-1))] HD2[p].
__global__ void __launch_bounds__(WGS, 1)
seq_main(const float* e1b, const float* e2b, const float* e3b, const float* d2b,
         const float* d3b, const float* keyb, const float* valb, float* dout,
         unsigned char* ws) {
  __shared__ unsigned short lds_s[32768];  // 64 KB
  unsigned short* lds = lds_s;

  const int wg = blockIdx.x, tid = threadIdx.x;
  const int wv = tid >> 6, lane = tid & 63;
  const int pair = wv >> 1, half = wv & 1;

  unsigned short* W = (unsigned short*)ws;
  const unsigned short* xh = (const unsigned short*)(ws + XPAD_HI_B);
  const unsigned short* xl = (const unsigned short*)(ws + XPAD_LO_B);
  unsigned char* st = ws + STATE_B;
  float* ringk = (float*)(ws + RINGK_B);
  float* ringv = (float*)(ws + RINGV_B);
  unsigned short* ctxh = (unsigned short*)(ws + CTXH_B);
  unsigned short* ctxl = (unsigned short*)(ws + CTXL_B);
  const float* d1bp = (const float*)(ws + D1BP_B);
  unsigned* C = (unsigned*)(st + BARO);
  auto CNT = [&](int l, int tt) { return C + l * 400 + tt; };

  auto hb = [&](size_t off, int par, int hl, int Hpad) {
    return (unsigned short*)(st + off) + (size_t)(par * 2 + hl) * 64 * Hpad;
  };
  auto bump = [&](int l, int tt) {
    if (tid == 0) __hip_atomic_fetch_add(CNT(l, tt), 1u, __ATOMIC_RELAXED, SCOPE_AGENT);
  };

  if (wg < 8) {  // ------------- e1 -------------
    const int ut = wg * 2 + pair;
    float c[4][4] = {{0.f}};
    for (int t = 0; t < 400; ++t) {
      const int p = t & 1, q = p ^ 1;
      f32x4 acc[4][4];
      zacc44(acc);
      // own chunk: HE1[q] (kwOff 96)
      if (tid == 0 && t >= 1) spin3(CNT(LE1, t - 1), 8, nullptr, 0, nullptr, 0);
      chunk_pass<256, 256>(lds, hb(HE1, q, 0, 256), hb(HE1, q, 1, 256), tid, lane, ut, 1, 256,
                           W + E1HI, W + E1LO, 352, 96, half, acc);
      // dep chunk: x(t) / hlast(t-1) (kwOff 0)
      if (tid == 0)
        spin3(t >= 21 ? CNT(LD3, t - 1) : nullptr, 3, t >= 2 ? CNT(LE2, t - 2) : nullptr, 8,
              nullptr, 0);
      if (t <= 20)
        chunk_pass<96, 128>(lds, xh + (size_t)t * 6144, xl + (size_t)t * 6144, tid, lane, ut, 1,
                            256, W + E1HI, W + E1LO, 352, 0, half, acc);
      else
        chunk_pass<96, 128>(lds, hb(HLAST, q, 0, 96), hb(HLAST, q, 1, 96), tid, lane, ut, 1,
                            256, W + E1HI, W + E1LO, 352, 0, half, acc);
      reduce_pair(lds, lane, pair, half, acc);
      if (!half)
        cell_update(lane, ut, 256, 256, e1b, acc, c, hb(HE1, p, 0, 256), hb(HE1, p, 1, 256),
                    nullptr);
      vm_drain();
      __syncthreads();
      bump(LE1, t);
    }
  } else if (wg < 16) {  // ------------- e2 -------------
    const int ut = (wg - 8) * 2 + pair;
    float c[4][4] = {{0.f}};
    for (int t = 0; t < 400; ++t) {
      const int p = t & 1, q = p ^ 1;
      f32x4 acc[4][4];
      zacc44(acc);
      if (tid == 0 && t >= 1) spin3(CNT(LE2, t - 1), 8, nullptr, 0, nullptr, 0);
      chunk_pass<256, 256>(lds, hb(HE2, q, 0, 256), hb(HE2, q, 1, 256), tid, lane, ut, 1, 256,
                           W + E2HI, W + E2LO, 512, 256, half, acc);
      if (tid == 0)
        spin3(CNT(LE1, t), 8, t >= 2 ? CNT(LE3, t - 2) : nullptr, 8, nullptr, 0);
      chunk_pass<256, 256>(lds, hb(HE1, p, 0, 256), hb(HE1, p, 1, 256), tid, lane, ut, 1, 256,
                           W + E2HI, W + E2LO, 512, 0, half, acc);
      reduce_pair(lds, lane, pair, half, acc);
      if (!half)
        cell_update(lane, ut, 256, 256, e2b, acc, c, hb(HE2, p, 0, 256), hb(HE2, p, 1, 256),
                    nullptr);
      vm_drain();
      __syncthreads();
      bump(LE2, t);
    }
  } else if (wg < 24) {  // ------------- e3 -------------
    const int ut = (wg - 16) * 2 + pair;
    float c[4][4] = {{0.f}};
    for (int t = 0; t < 400; ++t) {
      const int p = t & 1, q = p ^ 1;
      f32x4 acc[4][4];
      zacc44(acc);
      if (tid == 0 && t >= 1) spin3(CNT(LE3, t - 1), 8, nullptr, 0, nullptr, 0);
      chunk_pass<256, 256>(lds, hb(HE3, q, 0, 256), hb(HE3, q, 1, 256), tid, lane, ut, 1, 256,
                           W + E3HI, W + E3LO, 512, 256, half, acc);
      if (tid == 0)
        spin3(CNT(LE2, t), 8, t >= 2 ? CNT(LKV, t - 2) : nullptr, 8, nullptr, 0);
      chunk_pass<256, 256>(lds, hb(HE2, p, 0, 256), hb(HE2, p, 1, 256), tid, lane, ut, 1, 256,
                           W + E3HI, W + E3LO, 512, 0, half, acc);
      reduce_pair(lds, lane, pair, half, acc);
      if (!half)
        cell_update(lane, ut, 256, 256, e3b, acc, c, hb(HE3, p, 0, 256), hb(HE3, p, 1, 256),
                    nullptr);
      vm_drain();
      __syncthreads();
      bump(LE3, t);
    }
  } else if (wg < 32) {  // ------------- kv: 8 WGs (24-27 key, 28-31 val) -------------
    const bool isKey = wg < 28;
    const unsigned short* Whi = W + (isKey ? KHI : VHI);
    const unsigned short* Wlo = W + (isKey ? KLO : VLO);
    const float* bias = isKey ? keyb : valb;
    float* ring = isKey ? ringk : ringv;
    const int jt = (wg - (isKey ? 24 : 28)) * 4 + wv;
    const int col = lane & 15, kg = lane >> 4;
    for (int t = 0; t < 400; ++t) {
      const int p = t & 1;
      const int slot = t % 22;
      if (tid == 0)
        spin3(CNT(LE3, t), 8, t >= 22 ? CNT(LAT, t - 2) : nullptr, 16, nullptr, 0);
      __syncthreads();
      copy_hl<256, 256>(lds, hb(HE3, p, 0, 256), hb(HE3, p, 1, 256), tid);
      __syncthreads();
      float* outp = ring + (size_t)slot * 64 * 256;
      f32x4 acc[4];
#pragma unroll
      for (int m = 0; m < 4; m++) acc[m] = f32x4{0.f, 0.f, 0.f, 0.f};
      mfma_lin<256, 256>(lds, lane, jt, Whi, Wlo, 256, acc);
      int j = jt * 16 + col;
      float bj = bias[j];
#pragma unroll
      for (int m = 0; m < 4; m++)
#pragma unroll
        for (int r = 0; r < 4; r++) {
          int b = m * 16 + kg * 4 + r;
          st_sc_f32(outp + (size_t)b * 256 + j, acc[m][r] + bj);
        }
      vm_drain();
      __syncthreads();
      bump(LKV, t);
    }
  } else if (wg < 48) {  // ------------- attn: 16 WGs, 1 row/wave -------------
    const int b = (wg - 32) * 4 + wv;
    for (int t = 20; t < 400; ++t) {
      const int q = (t & 1) ^ 1;
      if (t == 20) {
        if (tid == 0) spin3(CNT(LKV, 20), 8, nullptr, 0, nullptr, 0);
        __syncthreads();
        // ctx := v20 (ring slot 20)
        const unsigned long long* vp =
            (const unsigned long long*)(ringv + ((size_t)20 * 64 + b) * 256 + lane * 4);
        unsigned long long v0 = ld_sc_u64(vp), v1 = ld_sc_u64(vp + 1);
        float f[4] = {__uint_as_float((unsigned)v0), __uint_as_float((unsigned)(v0 >> 32)),
                      __uint_as_float((unsigned)v1), __uint_as_float((unsigned)(v1 >> 32))};
        unsigned short hi[4], lo[4];
#pragma unroll
        for (int j = 0; j < 4; j++) f2hilo(f[j], hi[j], lo[j]);
        unsigned long long ph = (unsigned long long)hi[0] | ((unsigned long long)hi[1] << 16) |
                                ((unsigned long long)hi[2] << 32) |
                                ((unsigned long long)hi[3] << 48);
        unsigned long long pl = (unsigned long long)lo[0] | ((unsigned long long)lo[1] << 16) |
                                ((unsigned long long)lo[2] << 32) |
                                ((unsigned long long)lo[3] << 48);
        st_sc_u64((unsigned long long*)(ctxh + b * 256 + lane * 4), ph);
        st_sc_u64((unsigned long long*)(ctxl + b * 256 + lane * 4), pl);
      } else {
        if (tid == 0)
          spin3(CNT(LKV, t - 1), 8, CNT(LD2, t - 1), 8, CNT(LD1, t - 1), 8);
        __syncthreads();
        const unsigned short* qh = hb(HD2, q, 0, 256);
        const unsigned short* ql = hb(HD2, q, 1, 256);
        unsigned long long hq = ld_sc_u64((const unsigned long long*)(qh + b * 256 + lane * 4));
        unsigned long long lq = ld_sc_u64((const unsigned long long*)(ql + b * 256 + lane * 4));
        float qv[4];
#pragma unroll
        for (int j = 0; j < 4; j++)
          qv[j] = bf2f((unsigned short)(hq >> (16 * j))) + bf2f((unsigned short)(lq >> (16 * j)));
        float s[20];
#pragma unroll
        for (int i = 0; i < 20; i++) {
          int slot = (t - 20 + i) % 22;
          const unsigned long long* kp =
              (const unsigned long long*)(ringk + ((size_t)slot * 64 + b) * 256 + lane * 4);
          unsigned long long k0 = ld_sc_u64(kp), k1 = ld_sc_u64(kp + 1);
          s[i] = __uint_as_float((unsigned)k0) * qv[0] +
                 __uint_as_float((unsigned)(k0 >> 32)) * qv[1] +
                 __uint_as_float((unsigned)k1) * qv[2] +
                 __uint_as_float((unsigned)(k1 >> 32)) * qv[3];
        }
#pragma unroll
        for (int off = 32; off >= 1; off >>= 1)
#pragma unroll
          for (int i = 0; i < 20; i++) s[i] += __shfl_xor(s[i], off, 64);
        float mx = s[0];
#pragma unroll
        for (int i = 1; i < 20; i++) mx = fmaxf(mx, s[i]);
        float den = 0.f;
#pragma unroll
        for (int i = 0; i < 20; i++) {
          s[i] = __expf(s[i] - mx);
          den += s[i];
        }
        float inv = 1.f / den;
        float a0 = 0.f, a1 = 0.f, a2 = 0.f, a3 = 0.f;
#pragma unroll
        for (int i = 0; i < 20; i++) {
          int slot = (t - 20 + i) % 22;
          const unsigned long long* vp =
              (const unsigned long long*)(ringv + ((size_t)slot * 64 + b) * 256 + lane * 4);
          unsigned long long v0 = ld_sc_u64(vp), v1 = ld_sc_u64(vp + 1);
          a0 += s[i] * __uint_as_float((unsigned)v0);
          a1 += s[i] * __uint_as_float((unsigned)(v0 >> 32));
          a2 += s[i] * __uint_as_float((unsigned)v1);
          a3 += s[i] * __uint_as_float((unsigned)(v1 >> 32));
        }
        float f[4] = {a0 * inv, a1 * inv, a2 * inv, a3 * inv};
        unsigned short hi[4], lo[4];
#pragma unroll
        for (int j = 0; j < 4; j++) f2hilo(f[j], hi[j], lo[j]);
        unsigned long long ph = (unsigned long long)hi[0] | ((unsigned long long)hi[1] << 16) |
                                ((unsigned long long)hi[2] << 32) |
                                ((unsigned long long)hi[3] << 48);
        unsigned long long pl = (unsigned long long)lo[0] | ((unsigned long long)lo[1] << 16) |
                                ((unsigned long long)lo[2] << 32) |
                                ((unsigned long long)lo[3] << 48);
        st_sc_u64((unsigned long long*)(ctxh + b * 256 + lane * 4), ph);
        st_sc_u64((unsigned long long*)(ctxl + b * 256 + lane * 4), pl);
      }
      vm_drain();
      __syncthreads();
      bump(LAT, t);
    }
  } else if (wg < 56) {  // ------------- d1 (emb folded): Kp=608 -------------
    const int ut = (wg - 48) * 2 + pair;
    float c[4][4] = {{0.f}};
    for (int t = 20; t < 400; ++t) {
      const int p = t & 1, q = p ^ 1;
      f32x4 acc[4][4];
      zacc44(acc);
      // own chunk: HD1[q] (kwOff 352)
      if (tid == 0 && t >= 21) spin3(CNT(LD1, t - 1), 8, nullptr, 0, nullptr, 0);
      chunk_pass<256, 256>(lds, hb(HD1, q, 0, 256), hb(HD1, q, 1, 256), tid, lane, ut, 1, 256,
                           W + D1HI, W + D1LO, 608, 352, half, acc);
      // hlast chunk (kwOff 0)
      if (tid == 0 && t >= 21) spin3(CNT(LD3, t - 1), 3, nullptr, 0, nullptr, 0);
      if (t == 20)
        chunk_pass<96, 128>(lds, xh + (size_t)19 * 6144, xl + (size_t)19 * 6144, tid, lane, ut,
                            1, 256, W + D1HI, W + D1LO, 608, 0, half, acc);
      else
        chunk_pass<96, 128>(lds, hb(HLAST, q, 0, 96), hb(HLAST, q, 1, 96), tid, lane, ut, 1,
                            256, W + D1HI, W + D1LO, 608, 0, half, acc);
      // ctx chunk (kwOff 96) — freshest producer last
      if (tid == 0) spin3(CNT(LAT, t), 16, nullptr, 0, nullptr, 0);
      chunk_pass<256, 256>(lds, ctxh, ctxl, tid, lane, ut, 1, 256, W + D1HI, W + D1LO, 608, 96,
                           half, acc);
      reduce_pair(lds, lane, pair, half, acc);
      if (!half)
        cell_update(lane, ut, 256, 256, d1bp, acc, c, hb(HD1, p, 0, 256), hb(HD1, p, 1, 256),
                    nullptr);
      vm_drain();
      __syncthreads();
      bump(LD1, t);
    }
  } else if (wg < 64) {  // ------------- d2 -------------
    const int ut = (wg - 56) * 2 + pair;
    float c[4][4] = {{0.f}};
    for (int t = 20; t < 400; ++t) {
      const int p = t & 1, q = p ^ 1;
      f32x4 acc[4][4];
      zacc44(acc);
      if (tid == 0 && t >= 21) spin3(CNT(LD2, t - 1), 8, nullptr, 0, nullptr, 0);
      chunk_pass<256, 256>(lds, hb(HD2, q, 0, 256), hb(HD2, q, 1, 256), tid, lane, ut, 1, 256,
                           W + D2HI, W + D2LO, 512, 256, half, acc);
      if (tid == 0) spin3(CNT(LD1, t), 8, nullptr, 0, nullptr, 0);
      chunk_pass<256, 256>(lds, hb(HD1, p, 0, 256), hb(HD1, p, 1, 256), tid, lane, ut, 1, 256,
                           W + D2HI, W + D2LO, 512, 0, half, acc);
      reduce_pair(lds, lane, pair, half, acc);
      if (!half)
        cell_update(lane, ut, 256, 256, d2b, acc, c, hb(HD2, p, 0, 256), hb(HD2, p, 1, 256),
                    nullptr);
      vm_drain();
      __syncthreads();
      bump(LD2, t);
    }
  } else {  // ------------- d3: 3 WGs, ut 0..4 -------------
    const int ut = (wg - 64) * 2 + pair;
    const int utActive = (ut < 5) ? 1 : 0;
    float c[4][4] = {{0.f}};
    for (int t = 20; t < 400; ++t) {
      const int p = t & 1, q = p ^ 1;
      f32x4 acc[4][4];
      zacc44(acc);
      if (tid == 0 && t >= 21) spin3(CNT(LD3, t - 1), 3, nullptr, 0, nullptr, 0);
      chunk_pass<96, 128>(lds, hb(HLAST, q, 0, 96), hb(HLAST, q, 1, 96), tid, lane, ut, utActive,
                          80, W + D3HI, W + D3LO, 352, 256, half, acc);
      if (tid == 0) spin3(CNT(LD2, t), 8, nullptr, 0, nullptr, 0);
      chunk_pass<256, 256>(lds, hb(HD2, p, 0, 256), hb(HD2, p, 1, 256), tid, lane, ut, utActive,
                           80, W + D3HI, W + D3LO, 352, 0, half, acc);
      reduce_pair(lds, lane, pair, half, acc);
      if (!half && utActive)
        cell_update(lane, ut, 80, 96, d3b, acc, c, hb(HLAST, p, 0, 96), hb(HLAST, p, 1, 96),
                    dout + (size_t)(t - 20) * 80);
      vm_drain();
      __syncthreads();
      bump(LD3, t);
    }
  }
}

// ---------------- launch ----------------
extern "C" void kernel_launch(void* const* d_in, const int* in_sizes, int n_in, void* d_out,
                              int out_size, void* d_ws, size_t ws_size, hipStream_t stream) {
  if (ws_size < WS_NEED) return;

  const float* x = (const float*)d_in[0];
  const float* embW = (const float*)d_in[1];
  const float* embB = (const float*)d_in[2];
  const float* e1Wih = (const float*)d_in[3];
  const float* e1Whh = (const float*)d_in[4];
  const float* e1B = (const float*)d_in[5];
  const float* e2Wih = (const float*)d_in[6];
  const float* e2Whh = (const float*)d_in[7];
  const float* e2B = (const float*)d_in[8];
  const float* e3Wih = (const float*)d_in[9];
  const float* e3Whh = (const float*)d_in[10];
  const float* e3B = (const float*)d_in[11];
  const float* d1Wih = (const float*)d_in[12];
  const float* d1Whh = (const float*)d_in[13];
  const float* d1B = (const float*)d_in[14];
  const float* d2Wih = (const float*)d_in[15];
  const float* d2Whh = (const float*)d_in[16];
  const float* d2B = (const float*)d_in[17];
  const float* d3Wih = (const float*)d_in[18];
  const float* d3Whh = (const float*)d_in[19];
  const float* d3B = (const float*)d_in[20];
  const float* keyW = (const float*)d_in[21];
  const float* keyB = (const float*)d_in[22];
  const float* valW = (const float*)d_in[23];
  const float* valB = (const float*)d_in[24];

  unsigned char* ws = (unsigned char*)d_ws;
  unsigned short* W = (unsigned short*)ws;
  float* doutf = (float*)d_out;

  auto launch_w = [&](const float* wih, int din, const float* whh, int dh, int rows, int dinp,
                      int kp, size_t offhi, size_t offlo) {
    size_t tot = (size_t)rows * kp;
    int blocks = (int)((tot + 255) / 256);
    prep_w<<<blocks, 256, 0, stream>>>(wih, din, whh, dh, rows, dinp, kp, W + offhi, W + offlo);
  };
  launch_w(e1Wih, 80, e1Whh, 256, 1024, 96, 352, E1HI, E1LO);
  launch_w(e2Wih, 256, e2Whh, 256, 1024, 256, 512, E2HI, E2LO);
  launch_w(e3Wih, 256, e3Whh, 256, 1024, 256, 512, E3HI, E3LO);
  launch_w(d2Wih, 256, d2Whh, 256, 1024, 256, 512, D2HI, D2LO);
  launch_w(d3Wih, 256, d3Whh, 80, 320, 256, 352, D3HI, D3LO);
  launch_w(keyW, 256, nullptr, 0, 256, 256, 256, KHI, KLO);
  launch_w(valW, 256, nullptr, 0, 256, 256, 256, VHI, VLO);
  // d1 folded weights + bias
  {
    size_t tot = (size_t)1024 * 608;
    prep_d1_w<<<(int)((tot + 255) / 256), 256, 0, stream>>>(d1Wih, d1Whh, embW, W + D1HI,
                                                            W + D1LO);
    prep_d1_bias<<<4, 256, 0, stream>>>(d1Wih, embB, d1B, (float*)(ws + D1BP_B));
  }
  prep_x<<<(int)((XPAD_ELEMS + 255) / 256), 256, 0, stream>>>(
      x, (unsigned short*)(ws + XPAD_HI_B), (unsigned short*)(ws + XPAD_LO_B));
  hipMemsetAsync(ws + STATE_B, 0, STATE_BYTES, stream);

  seq_main<<<dim3(NWG), dim3(WGS), 0, stream>>>(e1B, e2B, e3B, d2B, d3B, keyB, valB, doutf, ws);
}